// Round 21
// baseline (266.450 us; speedup 1.0000x reference)
//
#include <hip/hip_runtime.h>
#include <hip/hip_bf16.h>

#define TOPK 30
#define NAT 14
#define EDGE_IN 3152   // 16 PE + 14*14*16 RBF
#define NCHUNK 99      // K chunks of 32 (3168 padded)
#define EPB 32         // edges per k_edge block (one wave, M=32)
#define KSPLIT 50      // ks=0: [0,50), ks=1: [50,99)
#define WT2N (NCHUNK * 8 * 64)          // 50688 fragment slices
#define WT2_BLOCKS ((WT2N + 255) / 256) // 198

typedef __attribute__((ext_vector_type(8))) short bf16x8;
typedef __attribute__((ext_vector_type(4))) float f32x4;

__device__ __forceinline__ unsigned short f2bf(float f) {
    union { float f; unsigned u; } v; v.f = f;
    unsigned r = v.u + 0x7FFF + ((v.u >> 16) & 1);   // RNE
    return (unsigned short)(r >> 16);
}
__device__ __forceinline__ float bf2f(unsigned short h) {
    union { unsigned u; float f; } v; v.u = ((unsigned)h) << 16;
    return v.f;
}
__device__ __forceinline__ short cvtbf(float f) {    // proven scalar path (116 VGPR)
    __hip_bfloat16 h = __float2bfloat16(f);
    return *reinterpret_cast<short*>(&h);
}

// ---------------- merged front: KNN [0,N) + Wt2 pack + Xa prep + node + ticket zero ----------------
__global__ __launch_bounds__(256) void k_front(const float* __restrict__ X, const float* __restrict__ mask,
                                               int* __restrict__ Eidx, float* __restrict__ outI,
                                               float* __restrict__ Xa,
                                               const float* __restrict__ EW, unsigned short* __restrict__ Wt2,
                                               const int* __restrict__ S, const float* __restrict__ BB,
                                               const float* __restrict__ NW, const float* __restrict__ nb,
                                               const float* __restrict__ ng, const float* __restrict__ nbe,
                                               float* __restrict__ outV, int* __restrict__ ticket,
                                               int nTick, int N) {
    __shared__ double sMax[4];
    __shared__ double sCd[128];
    __shared__ int    sCj[128];
    int b = blockIdx.x;
    if (b < N) {
        // ---- exact stable KNN in f64, two-phase register top-k (proven r13) ----
        int i = b, t = threadIdx.x;
        int w = t >> 6, ln = t & 63;
        double mi = (double)mask[i];
        double xx = (double)X[((size_t)i * NAT + 1) * 3 + 0];
        double xy = (double)X[((size_t)i * NAT + 1) * 3 + 1];
        double xz = (double)X[((size_t)i * NAT + 1) * 3 + 2];
        double dv[4], m2v[4];
        double lmax = -1.0;
#pragma unroll
        for (int k = 0; k < 4; k++) {
            int j = w * 256 + ln + 64 * k;
            if (j < N) {
                double dx = xx - (double)X[((size_t)j * NAT + 1) * 3 + 0];
                double dy = xy - (double)X[((size_t)j * NAT + 1) * 3 + 1];
                double dz = xz - (double)X[((size_t)j * NAT + 1) * 3 + 2];
                double sq = ((dx * dx + dy * dy) + dz * dz) + 1e-6;
                double m2 = mi * (double)mask[j];
                double d = m2 * sqrt(sq);
                dv[k] = d; m2v[k] = m2;
                lmax = fmax(lmax, d);
            } else { dv[k] = 1e300; m2v[k] = 1.0; }
        }
#pragma unroll
        for (int m = 32; m; m >>= 1) lmax = fmax(lmax, __shfl_xor(lmax, m));
        if (ln == 0) sMax[w] = lmax;
        __syncthreads();
        double Dmax = fmax(fmax(sMax[0], sMax[1]), fmax(sMax[2], sMax[3]));
#pragma unroll
        for (int k = 0; k < 4; k++) {
            int j = w * 256 + ln + 64 * k;
            if (j < N) dv[k] = dv[k] + 2.0 * (1.0 - m2v[k]) * Dmax;
        }
        for (int s = 0; s < TOPK; s++) {
            double bd = dv[0]; int bj = w * 256 + ln;
            if (dv[1] < bd) { bd = dv[1]; bj = w * 256 + ln + 64; }
            if (dv[2] < bd) { bd = dv[2]; bj = w * 256 + ln + 128; }
            if (dv[3] < bd) { bd = dv[3]; bj = w * 256 + ln + 192; }
#pragma unroll
            for (int m = 32; m; m >>= 1) {
                double od = __shfl_xor(bd, m);
                int oj = __shfl_xor(bj, m);
                if (od < bd || (od == bd && oj < bj)) { bd = od; bj = oj; }
            }
            if (ln == 0) { sCd[w * TOPK + s] = bd; sCj[w * TOPK + s] = bj; }
            int rel = bj - w * 256 - ln;
            if (rel == 0)        dv[0] = 1e300;
            else if (rel == 64)  dv[1] = 1e300;
            else if (rel == 128) dv[2] = 1e300;
            else if (rel == 192) dv[3] = 1e300;
        }
        __syncthreads();
        if (w == 0) {
            double c0 = (ln < 4 * TOPK) ? sCd[ln] : 1e300;
            int    j0 = (ln < 4 * TOPK) ? sCj[ln] : 0x7FFFFFFF;
            int l1 = ln + 64;
            double c1 = (l1 < 4 * TOPK) ? sCd[l1] : 1e300;
            int    j1 = (l1 < 4 * TOPK) ? sCj[l1] : 0x7FFFFFFF;
            for (int s = 0; s < TOPK; s++) {
                double bd = c0; int bj = j0;
                if (c1 < bd || (c1 == bd && j1 < bj)) { bd = c1; bj = j1; }
#pragma unroll
                for (int m = 32; m; m >>= 1) {
                    double od = __shfl_xor(bd, m);
                    int oj = __shfl_xor(bj, m);
                    if (od < bd || (od == bd && oj < bj)) { bd = od; bj = oj; }
                }
                if (ln == 0) {
                    Eidx[(size_t)i * TOPK + s] = bj;
                    outI[(size_t)i * TOPK + s] = (float)bj;
                }
                if (j0 == bj) c0 = 1e300;
                if (j1 == bj) c1 = 1e300;
            }
        }
        return;
    }
    b -= N;
    if (b < WT2_BLOCKS) {
        int gid = b * 256 + threadIdx.x;
        if (gid >= WT2N) return;
        int ln = gid & 63;
        int kcf = gid >> 6;
        int kc = kcf >> 3, f = kcf & 7;
        int c = f * 16 + (ln & 15);
        int k0 = kc * 32 + (ln >> 4) * 8;
        bf16x8 o;
#pragma unroll
        for (int e = 0; e < 8; e++) {
            int k = k0 + e;
            float v = (k < EDGE_IN) ? EW[(size_t)k * 128 + c] : 0.f;
            o[e] = (short)f2bf(v);
        }
        *reinterpret_cast<bf16x8*>(Wt2 + (size_t)gid * 8) = o;
        return;
    }
    b -= WT2_BLOCKS;
    int prepBlocks = (N + 255) / 256;
    if (b < prepBlocks) {
        int i = b * 256 + threadIdx.x;
        if (i >= N) return;
        const float* xi = X + (size_t)i * NAT * 3;
        float* xo = Xa + (size_t)i * NAT * 3;
        float Nx = xi[0], Ny = xi[1], Nz = xi[2];
        float Ax = xi[3], Ay = xi[4], Az = xi[5];
        float Cx = xi[6], Cy = xi[7], Cz = xi[8];
        float bx = Ax - Nx, by = Ay - Ny, bz = Az - Nz;
        float cx = Cx - Ax, cy = Cy - Ay, cz = Cz - Az;
        float ax = by * cz - bz * cy;
        float ay = bz * cx - bx * cz;
        float az = bx * cy - by * cx;
        float Cbx = -0.58273431f * ax + 0.56802827f * bx - 0.54067466f * cx + Ax;
        float Cby = -0.58273431f * ay + 0.56802827f * by - 0.54067466f * cy + Ay;
        float Cbz = -0.58273431f * az + 0.56802827f * bz - 0.54067466f * cz + Az;
#pragma unroll
        for (int a = 0; a < 4; a++) { xo[a*3] = xi[a*3]; xo[a*3+1] = xi[a*3+1]; xo[a*3+2] = xi[a*3+2]; }
        xo[12] = Cbx; xo[13] = Cby; xo[14] = Cbz;
#pragma unroll
        for (int a = 5; a < 14; a++) { xo[a*3] = xi[a*3]; xo[a*3+1] = xi[a*3+1]; xo[a*3+2] = xi[a*3+2]; }
        return;
    }
    b -= prepBlocks;
    int nodeBlocks = (N + 3) / 4;
    if (b < nodeBlocks) {
        int i = b * 4 + (threadIdx.x >> 6);
        if (i >= N) return;
        int t = threadIdx.x & 63;
        int s = S[i];
        float b0 = BB[i*6], b1 = BB[i*6+1], b2 = BB[i*6+2], b3 = BB[i*6+3], b4 = BB[i*6+4], b5 = BB[i*6+5];
        int t2 = t + 64;
        float x0 = NW[(size_t)s*128 + t] + nb[t]
                 + b0*NW[21*128+t] + b1*NW[22*128+t] + b2*NW[23*128+t]
                 + b3*NW[24*128+t] + b4*NW[25*128+t] + b5*NW[26*128+t];
        float x1 = NW[(size_t)s*128 + t2] + nb[t2]
                 + b0*NW[21*128+t2] + b1*NW[22*128+t2] + b2*NW[23*128+t2]
                 + b3*NW[24*128+t2] + b4*NW[25*128+t2] + b5*NW[26*128+t2];
        float sum = x0 + x1;
#pragma unroll
        for (int m = 32; m; m >>= 1) sum += __shfl_xor(sum, m);
        float mean = sum * (1.f / 128.f);
        float d0 = x0 - mean, d1 = x1 - mean;
        float vs = d0*d0 + d1*d1;
#pragma unroll
        for (int m = 32; m; m >>= 1) vs += __shfl_xor(vs, m);
        float inv = 1.f / sqrtf(vs * (1.f / 128.f) + 1e-5f);
        outV[(size_t)i*128 + t]  = d0 * inv * ng[t]  + nbe[t];
        outV[(size_t)i*128 + t2] = d1 * inv * ng[t2] + nbe[t2];
        return;
    }
    // last block: zero the per-edge-group tickets for this launch
    for (int k = threadIdx.x; k < nTick; k += 256) ticket[k] = 0;
}

// ---------------- A-fragment generator: proven scalar path, D passed in ----------------
__device__ __forceinline__ bf16x8 genA(int kb, float dpe, unsigned short du) {
    const float FR[8] = {1.0f, 0.31622776601683794f, 0.1f, 0.03162277660168379f,
                         0.01f, 0.0031622776601683794f, 0.001f, 0.00031622776601683794f};
    const float CS = 0.96089796f;   // 0.8*sqrt(log2 e)
    const float CJ = 1.28119728f;   // (4/3)*CS
    bf16x8 a;
    if (kb < 16) {
#pragma unroll
        for (int jj = 0; jj < 8; jj++) {
            float ang = dpe * FR[jj];
            a[jj] = cvtbf((kb == 0) ? cosf(ang) : sinf(ang));
        }
    } else if (kb >= EDGE_IN) {
#pragma unroll
        for (int jj = 0; jj < 8; jj++) a[jj] = 0;
    } else {
        float D = bf2f(du);
        float bse = (float)((kb - 16) & 15);
        float Dss = D * CS - bse * CJ;
#pragma unroll
        for (int jj = 0; jj < 8; jj++) {
            float u = Dss - (float)jj * CJ;
            a[jj] = cvtbf(__builtin_amdgcn_exp2f(-u * u));
        }
    }
    return a;
}

__device__ __forceinline__ int idxD(int kc, int koff) {
    int idx = 2 * kc + (koff >> 1) - 1;
    return idx < 0 ? 0 : (idx > 195 ? 195 : idx);
}

// ---------------- fused edge GEMM (K-split-2) + last-finisher LN reduction ----------------
// 1920 independent one-wave blocks: eb = bid>>1, ks = bid&1. Each publishes its
// f32 partial, fences, increments ticket[eb]; the SECOND finisher reads the
// partner partial, adds to its register acc, and runs the fused LN epilogue.
// No polling -> deadlock-free; f32 add is commutative -> bit-identical output.
__global__ __launch_bounds__(64) void k_edge(const float* __restrict__ Xa, const int* __restrict__ Eidx,
                                             const unsigned short* __restrict__ Wt2,
                                             float* __restrict__ P0, float* __restrict__ P1,
                                             int* __restrict__ ticket,
                                             const float* __restrict__ ebias, const float* __restrict__ egain,
                                             const float* __restrict__ ebeta,
                                             float* __restrict__ outE, int N) {
    __shared__ unsigned short sDh[EPB * 200];            // bf16 D table, 12.8 KB
    __shared__ float sDpe[EPB];
    const int NE = N * TOPK;
    int t = threadIdx.x;                 // 0..63, one wave
    int eb = blockIdx.x >> 1, ks = blockIdx.x & 1;
    int geBase = eb * EPB;
    int kc0 = ks ? KSPLIT : 0;
    int kcEnd = ks ? NCHUNK : KSPLIT;
    float* Pdst = ks ? P1 : P0;

    const unsigned short* gB = Wt2 + (size_t)t * 8;      // lane fragment base

    // prologue: issue first B chunk so it flies under the D-table build
    bf16x8 bA[8], bB[8];
#pragma unroll
    for (int f = 0; f < 8; f++)
        bA[f] = *reinterpret_cast<const bf16x8*>(gB + ((size_t)kc0 * 8 + f) * 512);

    // D-table build: 2 threads per edge, 98 pair-distances each
    {
        int le = t >> 1, q = t & 1;
        int ge = geBase + le; if (ge >= NE) ge = NE - 1;
        int i = ge / TOPK;
        int j = Eidx[ge];
        if (q == 0) sDpe[le] = (float)j - (float)i;
        const float* Xi = Xa + (size_t)i * NAT * 3;
        const float* Xj = Xa + (size_t)j * NAT * 3;
        for (int p = q; p < 196; p += 2) {
            int a = p / 14, b = p - 14 * a;
            float dx = Xi[a*3+0] - Xj[b*3+0];
            float dy = Xi[a*3+1] - Xj[b*3+1];
            float dz = Xi[a*3+2] - Xj[b*3+2];
            sDh[le * 200 + p] = f2bf(sqrtf(dx*dx + dy*dy + dz*dz + 1e-6f));
        }
    }
    asm volatile("s_waitcnt lgkmcnt(0)" ::: "memory");   // single wave: our ds_writes done

    int lrow = t & 15, koff = t >> 4;
    const unsigned short* sDrow0 = sDh + (size_t)lrow * 200;
    const unsigned short* sDrow1 = sDh + (size_t)(lrow + 16) * 200;
    float dpe0 = sDpe[lrow];
    float dpe1 = sDpe[lrow + 16];

    f32x4 acc0[8], acc1[8];
#pragma unroll
    for (int f = 0; f < 8; f++) { acc0[f] = (f32x4){0.f,0.f,0.f,0.f}; acc1[f] = (f32x4){0.f,0.f,0.f,0.f}; }

    // D pipeline prologue: chunks kc0, kc0+1, kc0+2
    int i0 = idxD(kc0, koff), i1 = idxD(kc0 + 1, koff), i2 = idxD(kc0 + 2, koff);
    unsigned short p0a = sDrow0[i0], p0b = sDrow1[i0];
    unsigned short p1a = sDrow0[i1], p1b = sDrow1[i1];
    unsigned short p2a = sDrow0[i2], p2b = sDrow1[i2];

    bf16x8 a0c = genA(kc0 * 32 + koff * 8, dpe0, p0a);
    bf16x8 a1c = genA(kc0 * 32 + koff * 8, dpe1, p0b);

    for (int kc = kc0; kc < kcEnd; kc += 2) {
        int i3 = idxD(kc + 3, koff);
        unsigned short p3a = sDrow0[i3], p3b = sDrow1[i3];
        bf16x8 a0n, a1n;
        if (kc + 1 < kcEnd) {
#pragma unroll
            for (int f = 0; f < 8; f++)
                bB[f] = *reinterpret_cast<const bf16x8*>(gB + ((size_t)(kc + 1) * 8 + f) * 512);
            int kb = (kc + 1) * 32 + koff * 8;
            a0n = genA(kb, dpe0, p1a);
            a1n = genA(kb, dpe1, p1b);
        }
#pragma unroll
        for (int f = 0; f < 8; f++) {
            acc0[f] = __builtin_amdgcn_mfma_f32_16x16x32_bf16(a0c, bA[f], acc0[f], 0, 0, 0);
            acc1[f] = __builtin_amdgcn_mfma_f32_16x16x32_bf16(a1c, bA[f], acc1[f], 0, 0, 0);
        }
        int i4 = idxD(kc + 4, koff);
        unsigned short p4a = sDrow0[i4], p4b = sDrow1[i4];
        if (kc + 2 < kcEnd) {
#pragma unroll
            for (int f = 0; f < 8; f++)
                bA[f] = *reinterpret_cast<const bf16x8*>(gB + ((size_t)(kc + 2) * 8 + f) * 512);
            int kb = (kc + 2) * 32 + koff * 8;
            a0c = genA(kb, dpe0, p2a);
            a1c = genA(kb, dpe1, p2b);
        }
        if (kc + 1 < kcEnd) {
#pragma unroll
            for (int f = 0; f < 8; f++) {
                acc0[f] = __builtin_amdgcn_mfma_f32_16x16x32_bf16(a0n, bB[f], acc0[f], 0, 0, 0);
                acc1[f] = __builtin_amdgcn_mfma_f32_16x16x32_bf16(a1n, bB[f], acc1[f], 0, 0, 0);
            }
        }
        p1a = p3a; p1b = p3b;
        p2a = p4a; p2b = p4b;
    }

    // ---- publish my partial ----
#pragma unroll
    for (int g2 = 0; g2 < 2; g2++) {
#pragma unroll
        for (int r = 0; r < 4; r++) {
            int row = geBase + g2 * 16 + koff * 4 + r;
            if (row < NE) {
                float* po = Pdst + (size_t)row * 128 + lrow;
#pragma unroll
                for (int f = 0; f < 8; f++) po[f * 16] = (g2 ? acc1[f][r] : acc0[f][r]);
            }
        }
    }
    __threadfence();                      // release: partial visible device-wide
    int old = 0;
    if (t == 0) old = atomicAdd(&ticket[eb], 1);
    old = __shfl(old, 0);
    if (old == 0) return;                 // first finisher done
    __threadfence();                      // acquire: partner's partial visible

    // ---- last finisher: add partner partial + bias, LN, store (r13-proven epilogue) ----
    const float* Psrc = ks ? P0 : P1;
    float gg[8], bb2[8], ebv[8];
#pragma unroll
    for (int f = 0; f < 8; f++) { int c = f * 16 + lrow; gg[f] = egain[c]; bb2[f] = ebeta[c]; ebv[f] = ebias[c]; }
#pragma unroll
    for (int g2 = 0; g2 < 2; g2++) {
#pragma unroll
        for (int r = 0; r < 4; r++) {
            int row = geBase + g2 * 16 + koff * 4 + r;
            if (row >= NE) continue;
            const float* ps = Psrc + (size_t)row * 128 + lrow;
            float x[8], sum = 0.f;
#pragma unroll
            for (int f = 0; f < 8; f++) {
                float v = (g2 ? acc1[f][r] : acc0[f][r]) + ps[f * 16] + ebv[f];
                x[f] = v; sum += v;
            }
#pragma unroll
            for (int m = 1; m < 16; m <<= 1) sum += __shfl_xor(sum, m);
            float mean = sum * (1.f / 128.f);
            float vs = 0.f;
#pragma unroll
            for (int f = 0; f < 8; f++) { float d2 = x[f] - mean; vs += d2 * d2; }
#pragma unroll
            for (int m = 1; m < 16; m <<= 1) vs += __shfl_xor(vs, m);
            float inv = 1.f / sqrtf(vs * (1.f / 128.f) + 1e-5f);
            float* po = outE + (size_t)row * 128 + lrow;
#pragma unroll
            for (int f = 0; f < 8; f++) po[f * 16] = (x[f] - mean) * inv * gg[f] + bb2[f];
        }
    }
}

extern "C" void kernel_launch(void* const* d_in, const int* in_sizes, int n_in,
                              void* d_out, int out_size, void* d_ws, size_t ws_size,
                              hipStream_t stream) {
    const float* X       = (const float*)d_in[0];
    const int*   S       = (const int*)d_in[1];
    const float* BB      = (const float*)d_in[2];
    const float* mask    = (const float*)d_in[3];
    const float* node_w  = (const float*)d_in[4];
    const float* node_b  = (const float*)d_in[5];
    const float* node_g  = (const float*)d_in[6];
    const float* node_lb = (const float*)d_in[7];
    const float* edge_w  = (const float*)d_in[8];
    const float* edge_b  = (const float*)d_in[9];
    const float* edge_g  = (const float*)d_in[10];
    const float* edge_lb = (const float*)d_in[11];
    int N  = in_sizes[1];       // 1024
    int NE = N * TOPK;
    int nTick = (NE + EPB - 1) / EPB;   // 960

    float* out  = (float*)d_out;
    float* outV = out;                                  // N*128 f32
    float* outE = out + (size_t)N * 128;                // NE*128 f32
    float* outI = outE + (size_t)NE * 128;              // NE f32

    char* ws = (char*)d_ws;
    int* Eidx = (int*)ws;
    size_t off = ((size_t)NE * 4 + 255) & ~(size_t)255;
    float* Xa = (float*)(ws + off);
    off += (((size_t)N * NAT * 3 * 4) + 255) & ~(size_t)255;
    unsigned short* Wt2 = (unsigned short*)(ws + off);  // WT2N*8 bf16 = 811008 B
    off += ((size_t)WT2N * 8 * 2 + 255) & ~(size_t)255;
    float* P0 = (float*)(ws + off);                     // NE*128 f32 partial (ks=0)
    off += (((size_t)NE * 128 * 4) + 255) & ~(size_t)255;
    float* P1 = (float*)(ws + off);                     // NE*128 f32 partial (ks=1)
    off += (((size_t)NE * 128 * 4) + 255) & ~(size_t)255;
    int* ticket = (int*)(ws + off);                     // nTick ints

    int prepBlocks = (N + 255) / 256;
    int nodeBlocks = (N + 3) / 4;
    int frontBlocks = N + WT2_BLOCKS + prepBlocks + nodeBlocks + 1;   // +1 ticket-zero block
    k_front<<<dim3(frontBlocks), dim3(256), 0, stream>>>(X, mask, Eidx, outI, Xa, edge_w, Wt2,
                                                         S, BB, node_w, node_b, node_g, node_lb,
                                                         outV, ticket, nTick, N);
    k_edge<<<dim3(nTick * 2), dim3(64), 0, stream>>>(Xa, Eidx, Wt2, P0, P1, ticket,
                                                     edge_b, edge_g, edge_lb, outE, N);
}

// Round 22
// 155.318 us; speedup vs baseline: 1.7155x; 1.7155x over previous
//
#include <hip/hip_runtime.h>
#include <hip/hip_bf16.h>

#define TOPK 30
#define NAT 14
#define EDGE_IN 3152   // 16 PE + 14*14*16 RBF
#define NCHUNK 99      // real K chunks of 32
#define WT2C 100       // Wt2 padded to 100 chunks (chunk 99 = zeros) -> uniform split-4
#define EPB 32         // edges per k_edge block (one wave, M=32)
#define KSPLIT 50      // fallback split-2: [0,50) / [50,99)
#define KCW4 25        // split-4: 4 x 25 chunks over padded 100
#define WT2N (WT2C * 8 * 64)            // 51200 fragment slices
#define WT2_BLOCKS ((WT2N + 255) / 256) // 200

typedef __attribute__((ext_vector_type(8))) short bf16x8;
typedef __attribute__((ext_vector_type(4))) float f32x4;

__device__ __forceinline__ unsigned short f2bf(float f) {
    union { float f; unsigned u; } v; v.f = f;
    unsigned r = v.u + 0x7FFF + ((v.u >> 16) & 1);   // RNE
    return (unsigned short)(r >> 16);
}
__device__ __forceinline__ float bf2f(unsigned short h) {
    union { unsigned u; float f; } v; v.u = ((unsigned)h) << 16;
    return v.f;
}
__device__ __forceinline__ short cvtbf(float f) {    // proven scalar path (116 VGPR)
    __hip_bfloat16 h = __float2bfloat16(f);
    return *reinterpret_cast<short*>(&h);
}

// ---------------- merged front: KNN [0,N) + Wt2 pack + Xa prep + node (r20-proven) ----------------
__global__ __launch_bounds__(256) void k_front(const float* __restrict__ X, const float* __restrict__ mask,
                                               int* __restrict__ Eidx, float* __restrict__ outI,
                                               float* __restrict__ Xa,
                                               const float* __restrict__ EW, unsigned short* __restrict__ Wt2,
                                               const int* __restrict__ S, const float* __restrict__ BB,
                                               const float* __restrict__ NW, const float* __restrict__ nb,
                                               const float* __restrict__ ng, const float* __restrict__ nbe,
                                               float* __restrict__ outV, int N) {
    __shared__ double sMax[4];
    __shared__ double sCd[128];
    __shared__ int    sCj[128];
    int b = blockIdx.x;
    if (b < N) {
        int i = b, t = threadIdx.x;
        int w = t >> 6, ln = t & 63;
        double mi = (double)mask[i];
        double xx = (double)X[((size_t)i * NAT + 1) * 3 + 0];
        double xy = (double)X[((size_t)i * NAT + 1) * 3 + 1];
        double xz = (double)X[((size_t)i * NAT + 1) * 3 + 2];
        double dv[4], m2v[4];
        double lmax = -1.0;
#pragma unroll
        for (int k = 0; k < 4; k++) {
            int j = w * 256 + ln + 64 * k;
            if (j < N) {
                double dx = xx - (double)X[((size_t)j * NAT + 1) * 3 + 0];
                double dy = xy - (double)X[((size_t)j * NAT + 1) * 3 + 1];
                double dz = xz - (double)X[((size_t)j * NAT + 1) * 3 + 2];
                double sq = ((dx * dx + dy * dy) + dz * dz) + 1e-6;
                double m2 = mi * (double)mask[j];
                double d = m2 * sqrt(sq);
                dv[k] = d; m2v[k] = m2;
                lmax = fmax(lmax, d);
            } else { dv[k] = 1e300; m2v[k] = 1.0; }
        }
#pragma unroll
        for (int m = 32; m; m >>= 1) lmax = fmax(lmax, __shfl_xor(lmax, m));
        if (ln == 0) sMax[w] = lmax;
        __syncthreads();
        double Dmax = fmax(fmax(sMax[0], sMax[1]), fmax(sMax[2], sMax[3]));
#pragma unroll
        for (int k = 0; k < 4; k++) {
            int j = w * 256 + ln + 64 * k;
            if (j < N) dv[k] = dv[k] + 2.0 * (1.0 - m2v[k]) * Dmax;
        }
        for (int s = 0; s < TOPK; s++) {
            double bd = dv[0]; int bj = w * 256 + ln;
            if (dv[1] < bd) { bd = dv[1]; bj = w * 256 + ln + 64; }
            if (dv[2] < bd) { bd = dv[2]; bj = w * 256 + ln + 128; }
            if (dv[3] < bd) { bd = dv[3]; bj = w * 256 + ln + 192; }
#pragma unroll
            for (int m = 32; m; m >>= 1) {
                double od = __shfl_xor(bd, m);
                int oj = __shfl_xor(bj, m);
                if (od < bd || (od == bd && oj < bj)) { bd = od; bj = oj; }
            }
            if (ln == 0) { sCd[w * TOPK + s] = bd; sCj[w * TOPK + s] = bj; }
            int rel = bj - w * 256 - ln;
            if (rel == 0)        dv[0] = 1e300;
            else if (rel == 64)  dv[1] = 1e300;
            else if (rel == 128) dv[2] = 1e300;
            else if (rel == 192) dv[3] = 1e300;
        }
        __syncthreads();
        if (w == 0) {
            double c0 = (ln < 4 * TOPK) ? sCd[ln] : 1e300;
            int    j0 = (ln < 4 * TOPK) ? sCj[ln] : 0x7FFFFFFF;
            int l1 = ln + 64;
            double c1 = (l1 < 4 * TOPK) ? sCd[l1] : 1e300;
            int    j1 = (l1 < 4 * TOPK) ? sCj[l1] : 0x7FFFFFFF;
            for (int s = 0; s < TOPK; s++) {
                double bd = c0; int bj = j0;
                if (c1 < bd || (c1 == bd && j1 < bj)) { bd = c1; bj = j1; }
#pragma unroll
                for (int m = 32; m; m >>= 1) {
                    double od = __shfl_xor(bd, m);
                    int oj = __shfl_xor(bj, m);
                    if (od < bd || (od == bd && oj < bj)) { bd = od; bj = oj; }
                }
                if (ln == 0) {
                    Eidx[(size_t)i * TOPK + s] = bj;
                    outI[(size_t)i * TOPK + s] = (float)bj;
                }
                if (j0 == bj) c0 = 1e300;
                if (j1 == bj) c1 = 1e300;
            }
        }
        return;
    }
    b -= N;
    if (b < WT2_BLOCKS) {
        int gid = b * 256 + threadIdx.x;
        if (gid >= WT2N) return;
        int ln = gid & 63;
        int kcf = gid >> 6;
        int kc = kcf >> 3, f = kcf & 7;
        int c = f * 16 + (ln & 15);
        int k0 = kc * 32 + (ln >> 4) * 8;
        bf16x8 o;
#pragma unroll
        for (int e = 0; e < 8; e++) {
            int k = k0 + e;
            float v = (k < EDGE_IN) ? EW[(size_t)k * 128 + c] : 0.f;
            o[e] = (short)f2bf(v);
        }
        *reinterpret_cast<bf16x8*>(Wt2 + (size_t)gid * 8) = o;
        return;
    }
    b -= WT2_BLOCKS;
    int prepBlocks = (N + 255) / 256;
    if (b < prepBlocks) {
        int i = b * 256 + threadIdx.x;
        if (i >= N) return;
        const float* xi = X + (size_t)i * NAT * 3;
        float* xo = Xa + (size_t)i * NAT * 3;
        float Nx = xi[0], Ny = xi[1], Nz = xi[2];
        float Ax = xi[3], Ay = xi[4], Az = xi[5];
        float Cx = xi[6], Cy = xi[7], Cz = xi[8];
        float bx = Ax - Nx, by = Ay - Ny, bz = Az - Nz;
        float cx = Cx - Ax, cy = Cy - Ay, cz = Cz - Az;
        float ax = by * cz - bz * cy;
        float ay = bz * cx - bx * cz;
        float az = bx * cy - by * cx;
        float Cbx = -0.58273431f * ax + 0.56802827f * bx - 0.54067466f * cx + Ax;
        float Cby = -0.58273431f * ay + 0.56802827f * by - 0.54067466f * cy + Ay;
        float Cbz = -0.58273431f * az + 0.56802827f * bz - 0.54067466f * cz + Az;
#pragma unroll
        for (int a = 0; a < 4; a++) { xo[a*3] = xi[a*3]; xo[a*3+1] = xi[a*3+1]; xo[a*3+2] = xi[a*3+2]; }
        xo[12] = Cbx; xo[13] = Cby; xo[14] = Cbz;
#pragma unroll
        for (int a = 5; a < 14; a++) { xo[a*3] = xi[a*3]; xo[a*3+1] = xi[a*3+1]; xo[a*3+2] = xi[a*3+2]; }
        return;
    }
    b -= prepBlocks;
    int i = b * 4 + (threadIdx.x >> 6);
    if (i >= N) return;
    int t = threadIdx.x & 63;
    int s = S[i];
    float b0 = BB[i*6], b1 = BB[i*6+1], b2 = BB[i*6+2], b3 = BB[i*6+3], b4 = BB[i*6+4], b5 = BB[i*6+5];
    int t2 = t + 64;
    float x0 = NW[(size_t)s*128 + t] + nb[t]
             + b0*NW[21*128+t] + b1*NW[22*128+t] + b2*NW[23*128+t]
             + b3*NW[24*128+t] + b4*NW[25*128+t] + b5*NW[26*128+t];
    float x1 = NW[(size_t)s*128 + t2] + nb[t2]
             + b0*NW[21*128+t2] + b1*NW[22*128+t2] + b2*NW[23*128+t2]
             + b3*NW[24*128+t2] + b4*NW[25*128+t2] + b5*NW[26*128+t2];
    float sum = x0 + x1;
#pragma unroll
    for (int m = 32; m; m >>= 1) sum += __shfl_xor(sum, m);
    float mean = sum * (1.f / 128.f);
    float d0 = x0 - mean, d1 = x1 - mean;
    float vs = d0*d0 + d1*d1;
#pragma unroll
    for (int m = 32; m; m >>= 1) vs += __shfl_xor(vs, m);
    float inv = 1.f / sqrtf(vs * (1.f / 128.f) + 1e-5f);
    outV[(size_t)i*128 + t]  = d0 * inv * ng[t]  + nbe[t];
    outV[(size_t)i*128 + t2] = d1 * inv * ng[t2] + nbe[t2];
}

// ---------------- A-fragment generator: proven scalar path, D passed in ----------------
__device__ __forceinline__ bf16x8 genA(int kb, float dpe, unsigned short du) {
    const float FR[8] = {1.0f, 0.31622776601683794f, 0.1f, 0.03162277660168379f,
                         0.01f, 0.0031622776601683794f, 0.001f, 0.00031622776601683794f};
    const float CS = 0.96089796f;   // 0.8*sqrt(log2 e)
    const float CJ = 1.28119728f;   // (4/3)*CS
    bf16x8 a;
    if (kb < 16) {
#pragma unroll
        for (int jj = 0; jj < 8; jj++) {
            float ang = dpe * FR[jj];
            a[jj] = cvtbf((kb == 0) ? cosf(ang) : sinf(ang));
        }
    } else if (kb >= EDGE_IN) {
#pragma unroll
        for (int jj = 0; jj < 8; jj++) a[jj] = 0;
    } else {
        float D = bf2f(du);
        float bse = (float)((kb - 16) & 15);
        float Dss = D * CS - bse * CJ;
#pragma unroll
        for (int jj = 0; jj < 8; jj++) {
            float u = Dss - (float)jj * CJ;
            a[jj] = cvtbf(__builtin_amdgcn_exp2f(-u * u));
        }
    }
    return a;
}

__device__ __forceinline__ int idxD(int kc, int koff) {
    int idx = 2 * kc + (koff >> 1) - 1;
    return idx < 0 ? 0 : (idx > 195 ? 195 : idx);
}

// ---------------- k_edge4: K-split-4, monolithic, UNIFORM f32 partials ----------------
// 3840 independent one-wave blocks: eb = bid>>2, ks = bid&3, chunks
// [25ks, 25ks+25) over the 100-chunk padded Wt2 (chunk 99 = zeros).
// Single store type (f32). Pdst: P0 (=outE) for ks=0, else P123 + (ks-1)*stride.
__global__ __launch_bounds__(64) void k_edge4(const float* __restrict__ Xa, const int* __restrict__ Eidx,
                                              const unsigned short* __restrict__ Wt2,
                                              float* __restrict__ P0, float* __restrict__ P123, int N) {
    __shared__ unsigned short sDh[EPB * 200];
    __shared__ float sDpe[EPB];
    const int NE = N * TOPK;
    int t = threadIdx.x;
    int eb = blockIdx.x >> 2, ks = blockIdx.x & 3;
    int geBase = eb * EPB;
    int kc0 = ks * KCW4;
    int kcEnd = kc0 + KCW4;
    size_t pstride = (size_t)NE * 128;
    float* Pdst = (ks == 0) ? P0 : (P123 + (size_t)(ks - 1) * pstride);

    const unsigned short* gB = Wt2 + (size_t)t * 8;

    bf16x8 bA[8], bB[8];
#pragma unroll
    for (int f = 0; f < 8; f++)
        bA[f] = *reinterpret_cast<const bf16x8*>(gB + ((size_t)kc0 * 8 + f) * 512);

    {
        int le = t >> 1, q = t & 1;
        int ge = geBase + le; if (ge >= NE) ge = NE - 1;
        int i = ge / TOPK;
        int j = Eidx[ge];
        if (q == 0) sDpe[le] = (float)j - (float)i;
        const float* Xi = Xa + (size_t)i * NAT * 3;
        const float* Xj = Xa + (size_t)j * NAT * 3;
        for (int p = q; p < 196; p += 2) {
            int a = p / 14, b2 = p - 14 * a;
            float dx = Xi[a*3+0] - Xj[b2*3+0];
            float dy = Xi[a*3+1] - Xj[b2*3+1];
            float dz = Xi[a*3+2] - Xj[b2*3+2];
            sDh[le * 200 + p] = f2bf(sqrtf(dx*dx + dy*dy + dz*dz + 1e-6f));
        }
    }
    asm volatile("s_waitcnt lgkmcnt(0)" ::: "memory");

    int lrow = t & 15, koff = t >> 4;
    const unsigned short* sDrow0 = sDh + (size_t)lrow * 200;
    const unsigned short* sDrow1 = sDh + (size_t)(lrow + 16) * 200;
    float dpe0 = sDpe[lrow];
    float dpe1 = sDpe[lrow + 16];

    f32x4 acc0[8], acc1[8];
#pragma unroll
    for (int f = 0; f < 8; f++) { acc0[f] = (f32x4){0.f,0.f,0.f,0.f}; acc1[f] = (f32x4){0.f,0.f,0.f,0.f}; }

    int i0 = idxD(kc0, koff), i1 = idxD(kc0 + 1, koff), i2 = idxD(kc0 + 2, koff);
    unsigned short p0a = sDrow0[i0], p0b = sDrow1[i0];
    unsigned short p1a = sDrow0[i1], p1b = sDrow1[i1];
    unsigned short p2a = sDrow0[i2], p2b = sDrow1[i2];

    bf16x8 a0c = genA(kc0 * 32 + koff * 8, dpe0, p0a);
    bf16x8 a1c = genA(kc0 * 32 + koff * 8, dpe1, p0b);

    for (int kc = kc0; kc < kcEnd; kc += 2) {
        int i3 = idxD(kc + 3, koff);
        unsigned short p3a = sDrow0[i3], p3b = sDrow1[i3];
        bf16x8 a0n, a1n;
        if (kc + 1 < kcEnd) {
#pragma unroll
            for (int f = 0; f < 8; f++)
                bB[f] = *reinterpret_cast<const bf16x8*>(gB + ((size_t)(kc + 1) * 8 + f) * 512);
            int kb = (kc + 1) * 32 + koff * 8;
            a0n = genA(kb, dpe0, p1a);
            a1n = genA(kb, dpe1, p1b);
        }
#pragma unroll
        for (int f = 0; f < 8; f++) {
            acc0[f] = __builtin_amdgcn_mfma_f32_16x16x32_bf16(a0c, bA[f], acc0[f], 0, 0, 0);
            acc1[f] = __builtin_amdgcn_mfma_f32_16x16x32_bf16(a1c, bA[f], acc1[f], 0, 0, 0);
        }
        int i4 = idxD(kc + 4, koff);
        unsigned short p4a = sDrow0[i4], p4b = sDrow1[i4];
        if (kc + 2 < kcEnd) {
#pragma unroll
            for (int f = 0; f < 8; f++)
                bA[f] = *reinterpret_cast<const bf16x8*>(gB + ((size_t)(kc + 2) * 8 + f) * 512);
            int kb = (kc + 2) * 32 + koff * 8;
            a0c = genA(kb, dpe0, p2a);
            a1c = genA(kb, dpe1, p2b);
        }
        if (kc + 1 < kcEnd) {
#pragma unroll
            for (int f = 0; f < 8; f++) {
                acc0[f] = __builtin_amdgcn_mfma_f32_16x16x32_bf16(a0n, bB[f], acc0[f], 0, 0, 0);
                acc1[f] = __builtin_amdgcn_mfma_f32_16x16x32_bf16(a1n, bB[f], acc1[f], 0, 0, 0);
            }
        }
        p1a = p3a; p1b = p3b;
        p2a = p4a; p2b = p4b;
    }

#pragma unroll
    for (int g2 = 0; g2 < 2; g2++) {
#pragma unroll
        for (int r = 0; r < 4; r++) {
            int row = geBase + g2 * 16 + koff * 4 + r;
            if (row < NE) {
                float* po = Pdst + (size_t)row * 128 + lrow;
#pragma unroll
                for (int f = 0; f < 8; f++) po[f * 16] = (g2 ? acc1[f][r] : acc0[f][r]);
            }
        }
    }
}

// ---------------- k_edge2: r20-verbatim K-split-2 fallback ----------------
__global__ __launch_bounds__(64) void k_edge2(const float* __restrict__ Xa, const int* __restrict__ Eidx,
                                              const unsigned short* __restrict__ Wt2,
                                              float* __restrict__ P0, float* __restrict__ P1, int N) {
    __shared__ unsigned short sDh[EPB * 200];
    __shared__ float sDpe[EPB];
    const int NE = N * TOPK;
    int t = threadIdx.x;
    int eb = blockIdx.x >> 1, ks = blockIdx.x & 1;
    int geBase = eb * EPB;
    int kc0 = ks ? KSPLIT : 0;
    int kcEnd = ks ? NCHUNK : KSPLIT;
    float* Pdst = ks ? P1 : P0;

    const unsigned short* gB = Wt2 + (size_t)t * 8;

    bf16x8 bA[8], bB[8];
#pragma unroll
    for (int f = 0; f < 8; f++)
        bA[f] = *reinterpret_cast<const bf16x8*>(gB + ((size_t)kc0 * 8 + f) * 512);

    {
        int le = t >> 1, q = t & 1;
        int ge = geBase + le; if (ge >= NE) ge = NE - 1;
        int i = ge / TOPK;
        int j = Eidx[ge];
        if (q == 0) sDpe[le] = (float)j - (float)i;
        const float* Xi = Xa + (size_t)i * NAT * 3;
        const float* Xj = Xa + (size_t)j * NAT * 3;
        for (int p = q; p < 196; p += 2) {
            int a = p / 14, b2 = p - 14 * a;
            float dx = Xi[a*3+0] - Xj[b2*3+0];
            float dy = Xi[a*3+1] - Xj[b2*3+1];
            float dz = Xi[a*3+2] - Xj[b2*3+2];
            sDh[le * 200 + p] = f2bf(sqrtf(dx*dx + dy*dy + dz*dz + 1e-6f));
        }
    }
    asm volatile("s_waitcnt lgkmcnt(0)" ::: "memory");

    int lrow = t & 15, koff = t >> 4;
    const unsigned short* sDrow0 = sDh + (size_t)lrow * 200;
    const unsigned short* sDrow1 = sDh + (size_t)(lrow + 16) * 200;
    float dpe0 = sDpe[lrow];
    float dpe1 = sDpe[lrow + 16];

    f32x4 acc0[8], acc1[8];
#pragma unroll
    for (int f = 0; f < 8; f++) { acc0[f] = (f32x4){0.f,0.f,0.f,0.f}; acc1[f] = (f32x4){0.f,0.f,0.f,0.f}; }

    int i0 = idxD(kc0, koff), i1 = idxD(kc0 + 1, koff), i2 = idxD(kc0 + 2, koff);
    unsigned short p0a = sDrow0[i0], p0b = sDrow1[i0];
    unsigned short p1a = sDrow0[i1], p1b = sDrow1[i1];
    unsigned short p2a = sDrow0[i2], p2b = sDrow1[i2];

    bf16x8 a0c = genA(kc0 * 32 + koff * 8, dpe0, p0a);
    bf16x8 a1c = genA(kc0 * 32 + koff * 8, dpe1, p0b);

    for (int kc = kc0; kc < kcEnd; kc += 2) {
        int i3 = idxD(kc + 3, koff);
        unsigned short p3a = sDrow0[i3], p3b = sDrow1[i3];
        bf16x8 a0n, a1n;
        if (kc + 1 < kcEnd) {
#pragma unroll
            for (int f = 0; f < 8; f++)
                bB[f] = *reinterpret_cast<const bf16x8*>(gB + ((size_t)(kc + 1) * 8 + f) * 512);
            int kb = (kc + 1) * 32 + koff * 8;
            a0n = genA(kb, dpe0, p1a);
            a1n = genA(kb, dpe1, p1b);
        }
#pragma unroll
        for (int f = 0; f < 8; f++) {
            acc0[f] = __builtin_amdgcn_mfma_f32_16x16x32_bf16(a0c, bA[f], acc0[f], 0, 0, 0);
            acc1[f] = __builtin_amdgcn_mfma_f32_16x16x32_bf16(a1c, bA[f], acc1[f], 0, 0, 0);
        }
        int i4 = idxD(kc + 4, koff);
        unsigned short p4a = sDrow0[i4], p4b = sDrow1[i4];
        if (kc + 2 < kcEnd) {
#pragma unroll
            for (int f = 0; f < 8; f++)
                bA[f] = *reinterpret_cast<const bf16x8*>(gB + ((size_t)(kc + 2) * 8 + f) * 512);
            int kb = (kc + 2) * 32 + koff * 8;
            a0c = genA(kb, dpe0, p2a);
            a1c = genA(kb, dpe1, p2b);
        }
        if (kc + 1 < kcEnd) {
#pragma unroll
            for (int f = 0; f < 8; f++) {
                acc0[f] = __builtin_amdgcn_mfma_f32_16x16x32_bf16(a0n, bB[f], acc0[f], 0, 0, 0);
                acc1[f] = __builtin_amdgcn_mfma_f32_16x16x32_bf16(a1n, bB[f], acc1[f], 0, 0, 0);
            }
        }
        p1a = p3a; p1b = p3b;
        p2a = p4a; p2b = p4b;
    }

#pragma unroll
    for (int g2 = 0; g2 < 2; g2++) {
#pragma unroll
        for (int r = 0; r < 4; r++) {
            int row = geBase + g2 * 16 + koff * 4 + r;
            if (row < NE) {
                float* po = Pdst + (size_t)row * 128 + lrow;
#pragma unroll
                for (int f = 0; f < 8; f++) po[f * 16] = (g2 ? acc1[f][r] : acc0[f][r]);
            }
        }
    }
}

// ---------------- reduce 4 partials + bias + LN ----------------
__global__ __launch_bounds__(64) void k_lnred4(const float* __restrict__ P0, const float* __restrict__ P123,
                                               size_t pstride,
                                               const float* __restrict__ eb, const float* __restrict__ gg,
                                               const float* __restrict__ bb, float* __restrict__ outE) {
    int row = blockIdx.x, t = threadIdx.x;
    int c0 = t, c1 = t + 64;
    size_t base = (size_t)row * 128;
    float x0 = P0[base + c0] + P123[base + c0] + P123[pstride + base + c0] + P123[2 * pstride + base + c0] + eb[c0];
    float x1 = P0[base + c1] + P123[base + c1] + P123[pstride + base + c1] + P123[2 * pstride + base + c1] + eb[c1];
    float sum = x0 + x1;
#pragma unroll
    for (int m = 32; m; m >>= 1) sum += __shfl_xor(sum, m);
    float mean = sum * (1.f / 128.f);
    float d0 = x0 - mean, d1 = x1 - mean;
    float vs = d0*d0 + d1*d1;
#pragma unroll
    for (int m = 32; m; m >>= 1) vs += __shfl_xor(vs, m);
    float inv = 1.f / sqrtf(vs * (1.f / 128.f) + 1e-5f);
    outE[base + c0] = d0 * inv * gg[c0] + bb[c0];
    outE[base + c1] = d1 * inv * gg[c1] + bb[c1];
}

// ---------------- reduce 2 partials + bias + LN (r20-verbatim fallback) ----------------
__global__ __launch_bounds__(64) void k_lnred2(const float* __restrict__ P0, const float* __restrict__ P1,
                                               const float* __restrict__ eb, const float* __restrict__ gg,
                                               const float* __restrict__ bb, float* __restrict__ outE) {
    int row = blockIdx.x, t = threadIdx.x;
    int c0 = t, c1 = t + 64;
    size_t base = (size_t)row * 128;
    float x0 = P0[base + c0] + P1[base + c0] + eb[c0];
    float x1 = P0[base + c1] + P1[base + c1] + eb[c1];
    float sum = x0 + x1;
#pragma unroll
    for (int m = 32; m; m >>= 1) sum += __shfl_xor(sum, m);
    float mean = sum * (1.f / 128.f);
    float d0 = x0 - mean, d1 = x1 - mean;
    float vs = d0*d0 + d1*d1;
#pragma unroll
    for (int m = 32; m; m >>= 1) vs += __shfl_xor(vs, m);
    float inv = 1.f / sqrtf(vs * (1.f / 128.f) + 1e-5f);
    outE[base + c0] = d0 * inv * gg[c0] + bb[c0];
    outE[base + c1] = d1 * inv * gg[c1] + bb[c1];
}

extern "C" void kernel_launch(void* const* d_in, const int* in_sizes, int n_in,
                              void* d_out, int out_size, void* d_ws, size_t ws_size,
                              hipStream_t stream) {
    const float* X       = (const float*)d_in[0];
    const int*   S       = (const int*)d_in[1];
    const float* BB      = (const float*)d_in[2];
    const float* mask    = (const float*)d_in[3];
    const float* node_w  = (const float*)d_in[4];
    const float* node_b  = (const float*)d_in[5];
    const float* node_g  = (const float*)d_in[6];
    const float* node_lb = (const float*)d_in[7];
    const float* edge_w  = (const float*)d_in[8];
    const float* edge_b  = (const float*)d_in[9];
    const float* edge_g  = (const float*)d_in[10];
    const float* edge_lb = (const float*)d_in[11];
    int N  = in_sizes[1];       // 1024
    int NE = N * TOPK;
    int nEB = (NE + EPB - 1) / EPB;     // 960

    float* out  = (float*)d_out;
    float* outV = out;                                  // N*128 f32
    float* outE = out + (size_t)N * 128;                // NE*128 f32 (doubles as P0)
    float* outI = outE + (size_t)NE * 128;              // NE f32

    char* ws = (char*)d_ws;
    int* Eidx = (int*)ws;
    size_t off = ((size_t)NE * 4 + 255) & ~(size_t)255;
    float* Xa = (float*)(ws + off);
    off += (((size_t)N * NAT * 3 * 4) + 255) & ~(size_t)255;
    unsigned short* Wt2 = (unsigned short*)(ws + off);  // WT2N*8 bf16 = 819200 B
    off += ((size_t)WT2N * 8 * 2 + 255) & ~(size_t)255;
    float* P123 = (float*)(ws + off);                   // up to 3 f32 partials, contiguous
    size_t pstride = (size_t)NE * 128;
    size_t need4 = off + 3 * pstride * 4;               // split-4 needs 3 extra partials
    bool use4 = (ws_size >= need4);

    int prepBlocks = (N + 255) / 256;
    int nodeBlocks = (N + 3) / 4;
    int frontBlocks = N + WT2_BLOCKS + prepBlocks + nodeBlocks;
    k_front<<<dim3(frontBlocks), dim3(256), 0, stream>>>(X, mask, Eidx, outI, Xa, edge_w, Wt2,
                                                         S, BB, node_w, node_b, node_g, node_lb, outV, N);
    if (use4) {
        k_edge4<<<dim3(nEB * 4), dim3(64), 0, stream>>>(Xa, Eidx, Wt2, outE, P123, N);
        k_lnred4<<<dim3(NE), dim3(64), 0, stream>>>(outE, P123, pstride, edge_b, edge_g, edge_lb, outE);
    } else {
        k_edge2<<<dim3(nEB * 2), dim3(64), 0, stream>>>(Xa, Eidx, Wt2, outE, P123, N);
        k_lnred2<<<dim3(NE), dim3(64), 0, stream>>>(outE, P123, edge_b, edge_g, edge_lb, outE);
    }
}

// Round 23
// 130.452 us; speedup vs baseline: 2.0425x; 1.1906x over previous
//
#include <hip/hip_runtime.h>
#include <hip/hip_bf16.h>

#define TOPK 30
#define NAT 14
#define EDGE_IN 3152   // 16 PE + 14*14*16 RBF
#define NCHUNK 99      // K chunks of 32 (3168 padded)
#define EPB 32         // edges per k_edge block (one wave, M=32)
#define KSPLIT 50      // ks=0: [0,50), ks=1: [50,99)
#define WT2N (NCHUNK * 8 * 64)          // 50688 fragment slices
#define WT2_BLOCKS ((WT2N + 255) / 256) // 198

typedef __attribute__((ext_vector_type(8))) short bf16x8;
typedef __attribute__((ext_vector_type(4))) float f32x4;

__device__ __forceinline__ unsigned short f2bf(float f) {
    union { float f; unsigned u; } v; v.f = f;
    unsigned r = v.u + 0x7FFF + ((v.u >> 16) & 1);   // RNE
    return (unsigned short)(r >> 16);
}
__device__ __forceinline__ float bf2f(unsigned short h) {
    union { unsigned u; float f; } v; v.u = ((unsigned)h) << 16;
    return v.f;
}
__device__ __forceinline__ short cvtbf(float f) {    // proven scalar path (116 VGPR)
    __hip_bfloat16 h = __float2bfloat16(f);
    return *reinterpret_cast<short*>(&h);
}

// ---------------- merged front: KNN [0,N) + Wt2 pack + Xa prep + node (r20-proven) ----------------
__global__ __launch_bounds__(256) void k_front(const float* __restrict__ X, const float* __restrict__ mask,
                                               int* __restrict__ Eidx, float* __restrict__ outI,
                                               float* __restrict__ Xa,
                                               const float* __restrict__ EW, unsigned short* __restrict__ Wt2,
                                               const int* __restrict__ S, const float* __restrict__ BB,
                                               const float* __restrict__ NW, const float* __restrict__ nb,
                                               const float* __restrict__ ng, const float* __restrict__ nbe,
                                               float* __restrict__ outV, int N) {
    __shared__ double sMax[4];
    __shared__ double sCd[128];
    __shared__ int    sCj[128];
    int b = blockIdx.x;
    if (b < N) {
        int i = b, t = threadIdx.x;
        int w = t >> 6, ln = t & 63;
        double mi = (double)mask[i];
        double xx = (double)X[((size_t)i * NAT + 1) * 3 + 0];
        double xy = (double)X[((size_t)i * NAT + 1) * 3 + 1];
        double xz = (double)X[((size_t)i * NAT + 1) * 3 + 2];
        double dv[4], m2v[4];
        double lmax = -1.0;
#pragma unroll
        for (int k = 0; k < 4; k++) {
            int j = w * 256 + ln + 64 * k;
            if (j < N) {
                double dx = xx - (double)X[((size_t)j * NAT + 1) * 3 + 0];
                double dy = xy - (double)X[((size_t)j * NAT + 1) * 3 + 1];
                double dz = xz - (double)X[((size_t)j * NAT + 1) * 3 + 2];
                double sq = ((dx * dx + dy * dy) + dz * dz) + 1e-6;
                double m2 = mi * (double)mask[j];
                double d = m2 * sqrt(sq);
                dv[k] = d; m2v[k] = m2;
                lmax = fmax(lmax, d);
            } else { dv[k] = 1e300; m2v[k] = 1.0; }
        }
#pragma unroll
        for (int m = 32; m; m >>= 1) lmax = fmax(lmax, __shfl_xor(lmax, m));
        if (ln == 0) sMax[w] = lmax;
        __syncthreads();
        double Dmax = fmax(fmax(sMax[0], sMax[1]), fmax(sMax[2], sMax[3]));
#pragma unroll
        for (int k = 0; k < 4; k++) {
            int j = w * 256 + ln + 64 * k;
            if (j < N) dv[k] = dv[k] + 2.0 * (1.0 - m2v[k]) * Dmax;
        }
        for (int s = 0; s < TOPK; s++) {
            double bd = dv[0]; int bj = w * 256 + ln;
            if (dv[1] < bd) { bd = dv[1]; bj = w * 256 + ln + 64; }
            if (dv[2] < bd) { bd = dv[2]; bj = w * 256 + ln + 128; }
            if (dv[3] < bd) { bd = dv[3]; bj = w * 256 + ln + 192; }
#pragma unroll
            for (int m = 32; m; m >>= 1) {
                double od = __shfl_xor(bd, m);
                int oj = __shfl_xor(bj, m);
                if (od < bd || (od == bd && oj < bj)) { bd = od; bj = oj; }
            }
            if (ln == 0) { sCd[w * TOPK + s] = bd; sCj[w * TOPK + s] = bj; }
            int rel = bj - w * 256 - ln;
            if (rel == 0)        dv[0] = 1e300;
            else if (rel == 64)  dv[1] = 1e300;
            else if (rel == 128) dv[2] = 1e300;
            else if (rel == 192) dv[3] = 1e300;
        }
        __syncthreads();
        if (w == 0) {
            double c0 = (ln < 4 * TOPK) ? sCd[ln] : 1e300;
            int    j0 = (ln < 4 * TOPK) ? sCj[ln] : 0x7FFFFFFF;
            int l1 = ln + 64;
            double c1 = (l1 < 4 * TOPK) ? sCd[l1] : 1e300;
            int    j1 = (l1 < 4 * TOPK) ? sCj[l1] : 0x7FFFFFFF;
            for (int s = 0; s < TOPK; s++) {
                double bd = c0; int bj = j0;
                if (c1 < bd || (c1 == bd && j1 < bj)) { bd = c1; bj = j1; }
#pragma unroll
                for (int m = 32; m; m >>= 1) {
                    double od = __shfl_xor(bd, m);
                    int oj = __shfl_xor(bj, m);
                    if (od < bd || (od == bd && oj < bj)) { bd = od; bj = oj; }
                }
                if (ln == 0) {
                    Eidx[(size_t)i * TOPK + s] = bj;
                    outI[(size_t)i * TOPK + s] = (float)bj;
                }
                if (j0 == bj) c0 = 1e300;
                if (j1 == bj) c1 = 1e300;
            }
        }
        return;
    }
    b -= N;
    if (b < WT2_BLOCKS) {
        int gid = b * 256 + threadIdx.x;
        if (gid >= WT2N) return;
        int ln = gid & 63;
        int kcf = gid >> 6;
        int kc = kcf >> 3, f = kcf & 7;
        int c = f * 16 + (ln & 15);
        int k0 = kc * 32 + (ln >> 4) * 8;
        bf16x8 o;
#pragma unroll
        for (int e = 0; e < 8; e++) {
            int k = k0 + e;
            float v = (k < EDGE_IN) ? EW[(size_t)k * 128 + c] : 0.f;
            o[e] = (short)f2bf(v);
        }
        *reinterpret_cast<bf16x8*>(Wt2 + (size_t)gid * 8) = o;
        return;
    }
    b -= WT2_BLOCKS;
    int prepBlocks = (N + 255) / 256;
    if (b < prepBlocks) {
        int i = b * 256 + threadIdx.x;
        if (i >= N) return;
        const float* xi = X + (size_t)i * NAT * 3;
        float* xo = Xa + (size_t)i * NAT * 3;
        float Nx = xi[0], Ny = xi[1], Nz = xi[2];
        float Ax = xi[3], Ay = xi[4], Az = xi[5];
        float Cx = xi[6], Cy = xi[7], Cz = xi[8];
        float bx = Ax - Nx, by = Ay - Ny, bz = Az - Nz;
        float cx = Cx - Ax, cy = Cy - Ay, cz = Cz - Az;
        float ax = by * cz - bz * cy;
        float ay = bz * cx - bx * cz;
        float az = bx * cy - by * cx;
        float Cbx = -0.58273431f * ax + 0.56802827f * bx - 0.54067466f * cx + Ax;
        float Cby = -0.58273431f * ay + 0.56802827f * by - 0.54067466f * cy + Ay;
        float Cbz = -0.58273431f * az + 0.56802827f * bz - 0.54067466f * cz + Az;
#pragma unroll
        for (int a = 0; a < 4; a++) { xo[a*3] = xi[a*3]; xo[a*3+1] = xi[a*3+1]; xo[a*3+2] = xi[a*3+2]; }
        xo[12] = Cbx; xo[13] = Cby; xo[14] = Cbz;
#pragma unroll
        for (int a = 5; a < 14; a++) { xo[a*3] = xi[a*3]; xo[a*3+1] = xi[a*3+1]; xo[a*3+2] = xi[a*3+2]; }
        return;
    }
    b -= prepBlocks;
    int i = b * 4 + (threadIdx.x >> 6);
    if (i >= N) return;
    int t = threadIdx.x & 63;
    int s = S[i];
    float b0 = BB[i*6], b1 = BB[i*6+1], b2 = BB[i*6+2], b3 = BB[i*6+3], b4 = BB[i*6+4], b5 = BB[i*6+5];
    int t2 = t + 64;
    float x0 = NW[(size_t)s*128 + t] + nb[t]
             + b0*NW[21*128+t] + b1*NW[22*128+t] + b2*NW[23*128+t]
             + b3*NW[24*128+t] + b4*NW[25*128+t] + b5*NW[26*128+t];
    float x1 = NW[(size_t)s*128 + t2] + nb[t2]
             + b0*NW[21*128+t2] + b1*NW[22*128+t2] + b2*NW[23*128+t2]
             + b3*NW[24*128+t2] + b4*NW[25*128+t2] + b5*NW[26*128+t2];
    float sum = x0 + x1;
#pragma unroll
    for (int m = 32; m; m >>= 1) sum += __shfl_xor(sum, m);
    float mean = sum * (1.f / 128.f);
    float d0 = x0 - mean, d1 = x1 - mean;
    float vs = d0*d0 + d1*d1;
#pragma unroll
    for (int m = 32; m; m >>= 1) vs += __shfl_xor(vs, m);
    float inv = 1.f / sqrtf(vs * (1.f / 128.f) + 1e-5f);
    outV[(size_t)i*128 + t]  = d0 * inv * ng[t]  + nbe[t];
    outV[(size_t)i*128 + t2] = d1 * inv * ng[t2] + nbe[t2];
}

// ---------------- A-fragment generator with Gaussian-ratio recurrence ----------------
// RBF: e_j = exp2(-(u0-j*CJ)^2). Ratios t_j = exp2(2*CJ*u0 - (2j+1)*CJ^2) obey
// t_{j+1} = t_j * Q1 (Q1 = exp2(-2*CJ^2)). Two independent 4-chains anchored at
// e0 and a fresh e4 (3 exp2 total, preserves ILP, no significant underflow loss).
__device__ __forceinline__ bf16x8 genA(int kb, float dpe, unsigned short du) {
    const float FR[8] = {1.0f, 0.31622776601683794f, 0.1f, 0.03162277660168379f,
                         0.01f, 0.0031622776601683794f, 0.001f, 0.00031622776601683794f};
    const float CS = 0.96089796f;     // 0.8*sqrt(log2 e)
    const float CJ = 1.28119728f;     // (4/3)*CS
    const float C2 = 1.6414664f;      // CJ^2
    const float TC = 2.5623946f;      // 2*CJ
    const float Q1 = 0.10272918f;     // exp2(-2*CJ^2)
    const float Q4 = 1.1141460e-4f;   // exp2(-8*CJ^2)
    bf16x8 a;
    if (kb < 16) {
#pragma unroll
        for (int jj = 0; jj < 8; jj++) {
            float ang = dpe * FR[jj];
            a[jj] = cvtbf((kb == 0) ? cosf(ang) : sinf(ang));
        }
    } else if (kb >= EDGE_IN) {
#pragma unroll
        for (int jj = 0; jj < 8; jj++) a[jj] = 0;
    } else {
        float D = bf2f(du);
        float bse = (float)((kb - 16) & 15);
        float u0 = fminf(D * CS - bse * CJ, 16.f);   // clamp: values beyond are < 2e-15
        float u4 = u0 - 4.f * CJ;
        float e0 = __builtin_amdgcn_exp2f(-u0 * u0);
        float t0 = __builtin_amdgcn_exp2f(TC * u0 - C2);
        float e4 = __builtin_amdgcn_exp2f(-u4 * u4);
        float t4 = t0 * Q4;
        float e1 = e0 * t0;  float t1 = t0 * Q1;
        float e2 = e1 * t1;  float t2 = t1 * Q1;
        float e3 = e2 * t2;
        float e5 = e4 * t4;  float t5 = t4 * Q1;
        float e6 = e5 * t5;  float t6 = t5 * Q1;
        float e7 = e6 * t6;
        a[0] = cvtbf(e0); a[1] = cvtbf(e1); a[2] = cvtbf(e2); a[3] = cvtbf(e3);
        a[4] = cvtbf(e4); a[5] = cvtbf(e5); a[6] = cvtbf(e6); a[7] = cvtbf(e7);
    }
    return a;
}

__device__ __forceinline__ int idxD(int kc, int koff) {
    int idx = 2 * kc + (koff >> 1) - 1;
    return idx < 0 ? 0 : (idx > 195 ? 195 : idx);
}

// ---------------- fused edge features + bf16 MFMA GEMM (K-split-2, r20-proven shape) ----------------
__global__ __launch_bounds__(64) void k_edge(const float* __restrict__ Xa, const int* __restrict__ Eidx,
                                             const unsigned short* __restrict__ Wt2,
                                             float* __restrict__ P0, float* __restrict__ P1, int N) {
    __shared__ unsigned short sDh[EPB * 200];            // bf16 D table, 12.8 KB
    __shared__ float sDpe[EPB];
    const int NE = N * TOPK;
    int t = threadIdx.x;                 // 0..63, one wave
    int eb = blockIdx.x >> 1, ks = blockIdx.x & 1;
    int geBase = eb * EPB;
    int kc0 = ks ? KSPLIT : 0;
    int kcEnd = ks ? NCHUNK : KSPLIT;
    float* Pdst = ks ? P1 : P0;

    const unsigned short* gB = Wt2 + (size_t)t * 8;      // lane fragment base

    bf16x8 bA[8], bB[8];
#pragma unroll
    for (int f = 0; f < 8; f++)
        bA[f] = *reinterpret_cast<const bf16x8*>(gB + ((size_t)kc0 * 8 + f) * 512);

    // D-table build: 2 threads per edge, 98 pair-distances each
    {
        int le = t >> 1, q = t & 1;
        int ge = geBase + le; if (ge >= NE) ge = NE - 1;
        int i = ge / TOPK;
        int j = Eidx[ge];
        if (q == 0) sDpe[le] = (float)j - (float)i;
        const float* Xi = Xa + (size_t)i * NAT * 3;
        const float* Xj = Xa + (size_t)j * NAT * 3;
        for (int p = q; p < 196; p += 2) {
            int a = p / 14, b2 = p - 14 * a;
            float dx = Xi[a*3+0] - Xj[b2*3+0];
            float dy = Xi[a*3+1] - Xj[b2*3+1];
            float dz = Xi[a*3+2] - Xj[b2*3+2];
            sDh[le * 200 + p] = f2bf(sqrtf(dx*dx + dy*dy + dz*dz + 1e-6f));
        }
    }
    asm volatile("s_waitcnt lgkmcnt(0)" ::: "memory");   // single wave: our ds_writes done

    int lrow = t & 15, koff = t >> 4;
    const unsigned short* sDrow0 = sDh + (size_t)lrow * 200;
    const unsigned short* sDrow1 = sDh + (size_t)(lrow + 16) * 200;
    float dpe0 = sDpe[lrow];
    float dpe1 = sDpe[lrow + 16];

    f32x4 acc0[8], acc1[8];
#pragma unroll
    for (int f = 0; f < 8; f++) { acc0[f] = (f32x4){0.f,0.f,0.f,0.f}; acc1[f] = (f32x4){0.f,0.f,0.f,0.f}; }

    int i0 = idxD(kc0, koff), i1 = idxD(kc0 + 1, koff), i2 = idxD(kc0 + 2, koff);
    unsigned short p0a = sDrow0[i0], p0b = sDrow1[i0];
    unsigned short p1a = sDrow0[i1], p1b = sDrow1[i1];
    unsigned short p2a = sDrow0[i2], p2b = sDrow1[i2];

    bf16x8 a0c = genA(kc0 * 32 + koff * 8, dpe0, p0a);
    bf16x8 a1c = genA(kc0 * 32 + koff * 8, dpe1, p0b);

    for (int kc = kc0; kc < kcEnd; kc += 2) {
        int i3 = idxD(kc + 3, koff);
        unsigned short p3a = sDrow0[i3], p3b = sDrow1[i3];
        bf16x8 a0n, a1n;
        if (kc + 1 < kcEnd) {
#pragma unroll
            for (int f = 0; f < 8; f++)
                bB[f] = *reinterpret_cast<const bf16x8*>(gB + ((size_t)(kc + 1) * 8 + f) * 512);
            int kb = (kc + 1) * 32 + koff * 8;
            a0n = genA(kb, dpe0, p1a);
            a1n = genA(kb, dpe1, p1b);
        }
#pragma unroll
        for (int f = 0; f < 8; f++) {
            acc0[f] = __builtin_amdgcn_mfma_f32_16x16x32_bf16(a0c, bA[f], acc0[f], 0, 0, 0);
            acc1[f] = __builtin_amdgcn_mfma_f32_16x16x32_bf16(a1c, bA[f], acc1[f], 0, 0, 0);
        }
        int i4 = idxD(kc + 4, koff);
        unsigned short p4a = sDrow0[i4], p4b = sDrow1[i4];
        if (kc + 2 < kcEnd) {
#pragma unroll
            for (int f = 0; f < 8; f++)
                bA[f] = *reinterpret_cast<const bf16x8*>(gB + ((size_t)(kc + 2) * 8 + f) * 512);
            int kb = (kc + 2) * 32 + koff * 8;
            a0c = genA(kb, dpe0, p2a);
            a1c = genA(kb, dpe1, p2b);
        }
        if (kc + 1 < kcEnd) {
#pragma unroll
            for (int f = 0; f < 8; f++) {
                acc0[f] = __builtin_amdgcn_mfma_f32_16x16x32_bf16(a0n, bB[f], acc0[f], 0, 0, 0);
                acc1[f] = __builtin_amdgcn_mfma_f32_16x16x32_bf16(a1n, bB[f], acc1[f], 0, 0, 0);
            }
        }
        p1a = p3a; p1b = p3b;
        p2a = p4a; p2b = p4b;
    }

    // write raw f32 partial
#pragma unroll
    for (int g2 = 0; g2 < 2; g2++) {
#pragma unroll
        for (int r = 0; r < 4; r++) {
            int row = geBase + g2 * 16 + koff * 4 + r;
            if (row < NE) {
                float* po = Pdst + (size_t)row * 128 + lrow;
#pragma unroll
                for (int f = 0; f < 8; f++) po[f * 16] = (g2 ? acc1[f][r] : acc0[f][r]);
            }
        }
    }
}

// ---------------- reduce partials + bias + LN (one wave per row, r20-verbatim) ----------------
__global__ __launch_bounds__(64) void k_lnred(const float* __restrict__ P0, const float* __restrict__ P1,
                                              const float* __restrict__ eb, const float* __restrict__ gg,
                                              const float* __restrict__ bb, float* __restrict__ outE) {
    int row = blockIdx.x, t = threadIdx.x;
    int c0 = t, c1 = t + 64;
    size_t base = (size_t)row * 128;
    float x0 = P0[base + c0] + P1[base + c0] + eb[c0];
    float x1 = P0[base + c1] + P1[base + c1] + eb[c1];
    float sum = x0 + x1;
#pragma unroll
    for (int m = 32; m; m >>= 1) sum += __shfl_xor(sum, m);
    float mean = sum * (1.f / 128.f);
    float d0 = x0 - mean, d1 = x1 - mean;
    float vs = d0*d0 + d1*d1;
#pragma unroll
    for (int m = 32; m; m >>= 1) vs += __shfl_xor(vs, m);
    float inv = 1.f / sqrtf(vs * (1.f / 128.f) + 1e-5f);
    outE[base + c0] = d0 * inv * gg[c0] + bb[c0];
    outE[base + c1] = d1 * inv * gg[c1] + bb[c1];
}

extern "C" void kernel_launch(void* const* d_in, const int* in_sizes, int n_in,
                              void* d_out, int out_size, void* d_ws, size_t ws_size,
                              hipStream_t stream) {
    const float* X       = (const float*)d_in[0];
    const int*   S       = (const int*)d_in[1];
    const float* BB      = (const float*)d_in[2];
    const float* mask    = (const float*)d_in[3];
    const float* node_w  = (const float*)d_in[4];
    const float* node_b  = (const float*)d_in[5];
    const float* node_g  = (const float*)d_in[6];
    const float* node_lb = (const float*)d_in[7];
    const float* edge_w  = (const float*)d_in[8];
    const float* edge_b  = (const float*)d_in[9];
    const float* edge_g  = (const float*)d_in[10];
    const float* edge_lb = (const float*)d_in[11];
    int N  = in_sizes[1];       // 1024
    int NE = N * TOPK;
    int nEB = (NE + EPB - 1) / EPB;     // 960

    float* out  = (float*)d_out;
    float* outV = out;                                  // N*128 f32
    float* outE = out + (size_t)N * 128;                // NE*128 f32 (doubles as P0)
    float* outI = outE + (size_t)NE * 128;              // NE f32

    char* ws = (char*)d_ws;
    int* Eidx = (int*)ws;
    size_t off = ((size_t)NE * 4 + 255) & ~(size_t)255;
    float* Xa = (float*)(ws + off);
    off += (((size_t)N * NAT * 3 * 4) + 255) & ~(size_t)255;
    unsigned short* Wt2 = (unsigned short*)(ws + off);  // WT2N*8 bf16 = 811008 B
    off += ((size_t)WT2N * 8 * 2 + 255) & ~(size_t)255;
    float* P1 = (float*)(ws + off);                     // NE*128 f32 = 15.73 MB partial

    int prepBlocks = (N + 255) / 256;
    int nodeBlocks = (N + 3) / 4;
    int frontBlocks = N + WT2_BLOCKS + prepBlocks + nodeBlocks;
    k_front<<<dim3(frontBlocks), dim3(256), 0, stream>>>(X, mask, Eidx, outI, Xa, edge_w, Wt2,
                                                         S, BB, node_w, node_b, node_g, node_lb, outV, N);
    k_edge<<<dim3(nEB * 2), dim3(64), 0, stream>>>(Xa, Eidx, Wt2, outE, P1, N);
    k_lnred<<<dim3(NE), dim3(64), 0, stream>>>(outE, P1, edge_b, edge_g, edge_lb, outE);
}

// Round 24
// 130.381 us; speedup vs baseline: 2.0436x; 1.0005x over previous
//
#include <hip/hip_runtime.h>
#include <hip/hip_bf16.h>

#define TOPK 30
#define NAT 14
#define EDGE_IN 3152   // 16 PE + 14*14*16 RBF
#define NCHUNK 99      // K chunks of 32 (3168 padded)
#define EPB 32         // edges per k_edge block (one wave, M=32)
#define KSPLIT 50      // ks=0: [0,50), ks=1: [50,99)
#define WT2N (NCHUNK * 8 * 64)          // 50688 fragment slices
#define WT2_BLOCKS ((WT2N + 255) / 256) // 198

typedef __attribute__((ext_vector_type(8))) short bf16x8;
typedef __attribute__((ext_vector_type(4))) float f32x4;

__device__ __forceinline__ unsigned short f2bf(float f) {
    union { float f; unsigned u; } v; v.f = f;
    unsigned r = v.u + 0x7FFF + ((v.u >> 16) & 1);   // RNE
    return (unsigned short)(r >> 16);
}
__device__ __forceinline__ float bf2f(unsigned short h) {
    union { unsigned u; float f; } v; v.u = ((unsigned)h) << 16;
    return v.f;
}
__device__ __forceinline__ short cvtbf(float f) {    // proven scalar path (116 VGPR)
    __hip_bfloat16 h = __float2bfloat16(f);
    return *reinterpret_cast<short*>(&h);
}

// ---------------- merged front: KNN [0,N) + Wt2 pack + Xa prep + node ----------------
// KNN orders by squared distance s (sqrt is monotonic -> identical ranking for
// binary masks); masked pairs get key 1e300 (reference's 2*Dmax exceeds all
// unmasked D; ties resolve by index identically). Removes all f64 sqrt and the
// whole Dmax reduce/adjust pass.
__global__ __launch_bounds__(256) void k_front(const float* __restrict__ X, const float* __restrict__ mask,
                                               int* __restrict__ Eidx, float* __restrict__ outI,
                                               float* __restrict__ Xa,
                                               const float* __restrict__ EW, unsigned short* __restrict__ Wt2,
                                               const int* __restrict__ S, const float* __restrict__ BB,
                                               const float* __restrict__ NW, const float* __restrict__ nb,
                                               const float* __restrict__ ng, const float* __restrict__ nbe,
                                               float* __restrict__ outV, int N) {
    __shared__ double sCd[128];
    __shared__ int    sCj[128];
    int b = blockIdx.x;
    if (b < N) {
        int i = b, t = threadIdx.x;
        int w = t >> 6, ln = t & 63;
        double mi = (double)mask[i];
        double xx = (double)X[((size_t)i * NAT + 1) * 3 + 0];
        double xy = (double)X[((size_t)i * NAT + 1) * 3 + 1];
        double xz = (double)X[((size_t)i * NAT + 1) * 3 + 2];
        double dv[4];
#pragma unroll
        for (int k = 0; k < 4; k++) {
            int j = w * 256 + ln + 64 * k;
            if (j < N) {
                double dx = xx - (double)X[((size_t)j * NAT + 1) * 3 + 0];
                double dy = xy - (double)X[((size_t)j * NAT + 1) * 3 + 1];
                double dz = xz - (double)X[((size_t)j * NAT + 1) * 3 + 2];
                double sq = ((dx * dx + dy * dy) + dz * dz) + 1e-6;
                double m2 = mi * (double)mask[j];
                dv[k] = (m2 == 0.0) ? 1e300 : sq;   // order-equivalent key
            } else dv[k] = 1e300;
        }
        // phase 1: per-wave top-30, registers + butterflies only
        for (int s = 0; s < TOPK; s++) {
            double bd = dv[0]; int bj = w * 256 + ln;
            if (dv[1] < bd) { bd = dv[1]; bj = w * 256 + ln + 64; }
            if (dv[2] < bd) { bd = dv[2]; bj = w * 256 + ln + 128; }
            if (dv[3] < bd) { bd = dv[3]; bj = w * 256 + ln + 192; }
#pragma unroll
            for (int m = 32; m; m >>= 1) {
                double od = __shfl_xor(bd, m);
                int oj = __shfl_xor(bj, m);
                if (od < bd || (od == bd && oj < bj)) { bd = od; bj = oj; }
            }
            if (ln == 0) { sCd[w * TOPK + s] = bd; sCj[w * TOPK + s] = bj; }
            int rel = bj - w * 256 - ln;
            if (rel == 0)        dv[0] = 1e301;
            else if (rel == 64)  dv[1] = 1e301;
            else if (rel == 128) dv[2] = 1e301;
            else if (rel == 192) dv[3] = 1e301;
        }
        __syncthreads();
        // phase 2: wave 0 merges 120 candidates
        if (w == 0) {
            double c0 = (ln < 4 * TOPK) ? sCd[ln] : 1e301;
            int    j0 = (ln < 4 * TOPK) ? sCj[ln] : 0x7FFFFFFF;
            int l1 = ln + 64;
            double c1 = (l1 < 4 * TOPK) ? sCd[l1] : 1e301;
            int    j1 = (l1 < 4 * TOPK) ? sCj[l1] : 0x7FFFFFFF;
            for (int s = 0; s < TOPK; s++) {
                double bd = c0; int bj = j0;
                if (c1 < bd || (c1 == bd && j1 < bj)) { bd = c1; bj = j1; }
#pragma unroll
                for (int m = 32; m; m >>= 1) {
                    double od = __shfl_xor(bd, m);
                    int oj = __shfl_xor(bj, m);
                    if (od < bd || (od == bd && oj < bj)) { bd = od; bj = oj; }
                }
                if (ln == 0) {
                    Eidx[(size_t)i * TOPK + s] = bj;
                    outI[(size_t)i * TOPK + s] = (float)bj;
                }
                if (j0 == bj) c0 = 1e301;
                if (j1 == bj) c1 = 1e301;
            }
        }
        return;
    }
    b -= N;
    if (b < WT2_BLOCKS) {
        int gid = b * 256 + threadIdx.x;
        if (gid >= WT2N) return;
        int ln = gid & 63;
        int kcf = gid >> 6;
        int kc = kcf >> 3, f = kcf & 7;
        int c = f * 16 + (ln & 15);
        int k0 = kc * 32 + (ln >> 4) * 8;
        bf16x8 o;
#pragma unroll
        for (int e = 0; e < 8; e++) {
            int k = k0 + e;
            float v = (k < EDGE_IN) ? EW[(size_t)k * 128 + c] : 0.f;
            o[e] = (short)f2bf(v);
        }
        *reinterpret_cast<bf16x8*>(Wt2 + (size_t)gid * 8) = o;
        return;
    }
    b -= WT2_BLOCKS;
    int prepBlocks = (N + 255) / 256;
    if (b < prepBlocks) {
        int i = b * 256 + threadIdx.x;
        if (i >= N) return;
        const float* xi = X + (size_t)i * NAT * 3;
        float* xo = Xa + (size_t)i * NAT * 3;
        float Nx = xi[0], Ny = xi[1], Nz = xi[2];
        float Ax = xi[3], Ay = xi[4], Az = xi[5];
        float Cx = xi[6], Cy = xi[7], Cz = xi[8];
        float bx = Ax - Nx, by = Ay - Ny, bz = Az - Nz;
        float cx = Cx - Ax, cy = Cy - Ay, cz = Cz - Az;
        float ax = by * cz - bz * cy;
        float ay = bz * cx - bx * cz;
        float az = bx * cy - by * cx;
        float Cbx = -0.58273431f * ax + 0.56802827f * bx - 0.54067466f * cx + Ax;
        float Cby = -0.58273431f * ay + 0.56802827f * by - 0.54067466f * cy + Ay;
        float Cbz = -0.58273431f * az + 0.56802827f * bz - 0.54067466f * cz + Az;
#pragma unroll
        for (int a = 0; a < 4; a++) { xo[a*3] = xi[a*3]; xo[a*3+1] = xi[a*3+1]; xo[a*3+2] = xi[a*3+2]; }
        xo[12] = Cbx; xo[13] = Cby; xo[14] = Cbz;
#pragma unroll
        for (int a = 5; a < 14; a++) { xo[a*3] = xi[a*3]; xo[a*3+1] = xi[a*3+1]; xo[a*3+2] = xi[a*3+2]; }
        return;
    }
    b -= prepBlocks;
    int i = b * 4 + (threadIdx.x >> 6);
    if (i >= N) return;
    int t = threadIdx.x & 63;
    int s = S[i];
    float b0 = BB[i*6], b1 = BB[i*6+1], b2 = BB[i*6+2], b3 = BB[i*6+3], b4 = BB[i*6+4], b5 = BB[i*6+5];
    int t2 = t + 64;
    float x0 = NW[(size_t)s*128 + t] + nb[t]
             + b0*NW[21*128+t] + b1*NW[22*128+t] + b2*NW[23*128+t]
             + b3*NW[24*128+t] + b4*NW[25*128+t] + b5*NW[26*128+t];
    float x1 = NW[(size_t)s*128 + t2] + nb[t2]
             + b0*NW[21*128+t2] + b1*NW[22*128+t2] + b2*NW[23*128+t2]
             + b3*NW[24*128+t2] + b4*NW[25*128+t2] + b5*NW[26*128+t2];
    float sum = x0 + x1;
#pragma unroll
    for (int m = 32; m; m >>= 1) sum += __shfl_xor(sum, m);
    float mean = sum * (1.f / 128.f);
    float d0 = x0 - mean, d1 = x1 - mean;
    float vs = d0*d0 + d1*d1;
#pragma unroll
    for (int m = 32; m; m >>= 1) vs += __shfl_xor(vs, m);
    float inv = 1.f / sqrtf(vs * (1.f / 128.f) + 1e-5f);
    outV[(size_t)i*128 + t]  = d0 * inv * ng[t]  + nbe[t];
    outV[(size_t)i*128 + t2] = d1 * inv * ng[t2] + nbe[t2];
}

// ---------------- A-fragment generator with Gaussian-ratio recurrence (r23-proven) ----------------
__device__ __forceinline__ bf16x8 genA(int kb, float dpe, unsigned short du) {
    const float FR[8] = {1.0f, 0.31622776601683794f, 0.1f, 0.03162277660168379f,
                         0.01f, 0.0031622776601683794f, 0.001f, 0.00031622776601683794f};
    const float CS = 0.96089796f;     // 0.8*sqrt(log2 e)
    const float CJ = 1.28119728f;     // (4/3)*CS
    const float C2 = 1.6414664f;      // CJ^2
    const float TC = 2.5623946f;      // 2*CJ
    const float Q1 = 0.10272918f;     // exp2(-2*CJ^2)
    const float Q4 = 1.1141460e-4f;   // exp2(-8*CJ^2)
    bf16x8 a;
    if (kb < 16) {
#pragma unroll
        for (int jj = 0; jj < 8; jj++) {
            float ang = dpe * FR[jj];
            a[jj] = cvtbf((kb == 0) ? cosf(ang) : sinf(ang));
        }
    } else if (kb >= EDGE_IN) {
#pragma unroll
        for (int jj = 0; jj < 8; jj++) a[jj] = 0;
    } else {
        float D = bf2f(du);
        float bse = (float)((kb - 16) & 15);
        float u0 = fminf(D * CS - bse * CJ, 16.f);   // clamp: beyond -> < 2e-15
        float u4 = u0 - 4.f * CJ;
        float e0 = __builtin_amdgcn_exp2f(-u0 * u0);
        float t0 = __builtin_amdgcn_exp2f(TC * u0 - C2);
        float e4 = __builtin_amdgcn_exp2f(-u4 * u4);
        float t4 = t0 * Q4;
        float e1 = e0 * t0;  float t1 = t0 * Q1;
        float e2 = e1 * t1;  float t2 = t1 * Q1;
        float e3 = e2 * t2;
        float e5 = e4 * t4;  float t5 = t4 * Q1;
        float e6 = e5 * t5;  float t6 = t5 * Q1;
        float e7 = e6 * t6;
        a[0] = cvtbf(e0); a[1] = cvtbf(e1); a[2] = cvtbf(e2); a[3] = cvtbf(e3);
        a[4] = cvtbf(e4); a[5] = cvtbf(e5); a[6] = cvtbf(e6); a[7] = cvtbf(e7);
    }
    return a;
}

__device__ __forceinline__ int idxD(int kc, int koff) {
    int idx = 2 * kc + (koff >> 1) - 1;
    return idx < 0 ? 0 : (idx > 195 ? 195 : idx);
}

// ---------------- fused edge features + bf16 MFMA GEMM (K-split-2, r20/r23-proven shape) ----------------
__global__ __launch_bounds__(64) void k_edge(const float* __restrict__ Xa, const int* __restrict__ Eidx,
                                             const unsigned short* __restrict__ Wt2,
                                             float* __restrict__ P0, float* __restrict__ P1, int N) {
    __shared__ unsigned short sDh[EPB * 200];            // bf16 D table, 12.8 KB
    __shared__ float sDpe[EPB];
    const int NE = N * TOPK;
    int t = threadIdx.x;                 // 0..63, one wave
    int eb = blockIdx.x >> 1, ks = blockIdx.x & 1;
    int geBase = eb * EPB;
    int kc0 = ks ? KSPLIT : 0;
    int kcEnd = ks ? NCHUNK : KSPLIT;
    float* Pdst = ks ? P1 : P0;

    const unsigned short* gB = Wt2 + (size_t)t * 8;      // lane fragment base

    bf16x8 bA[8], bB[8];
#pragma unroll
    for (int f = 0; f < 8; f++)
        bA[f] = *reinterpret_cast<const bf16x8*>(gB + ((size_t)kc0 * 8 + f) * 512);

    // D-table build: 2 threads per edge, 98 pair-distances each
    {
        int le = t >> 1, q = t & 1;
        int ge = geBase + le; if (ge >= NE) ge = NE - 1;
        int i = ge / TOPK;
        int j = Eidx[ge];
        if (q == 0) sDpe[le] = (float)j - (float)i;
        const float* Xi = Xa + (size_t)i * NAT * 3;
        const float* Xj = Xa + (size_t)j * NAT * 3;
        for (int p = q; p < 196; p += 2) {
            int a = p / 14, b2 = p - 14 * a;
            float dx = Xi[a*3+0] - Xj[b2*3+0];
            float dy = Xi[a*3+1] - Xj[b2*3+1];
            float dz = Xi[a*3+2] - Xj[b2*3+2];
            sDh[le * 200 + p] = f2bf(sqrtf(dx*dx + dy*dy + dz*dz + 1e-6f));
        }
    }
    asm volatile("s_waitcnt lgkmcnt(0)" ::: "memory");   // single wave: our ds_writes done

    int lrow = t & 15, koff = t >> 4;
    const unsigned short* sDrow0 = sDh + (size_t)lrow * 200;
    const unsigned short* sDrow1 = sDh + (size_t)(lrow + 16) * 200;
    float dpe0 = sDpe[lrow];
    float dpe1 = sDpe[lrow + 16];

    f32x4 acc0[8], acc1[8];
#pragma unroll
    for (int f = 0; f < 8; f++) { acc0[f] = (f32x4){0.f,0.f,0.f,0.f}; acc1[f] = (f32x4){0.f,0.f,0.f,0.f}; }

    int i0 = idxD(kc0, koff), i1 = idxD(kc0 + 1, koff), i2 = idxD(kc0 + 2, koff);
    unsigned short p0a = sDrow0[i0], p0b = sDrow1[i0];
    unsigned short p1a = sDrow0[i1], p1b = sDrow1[i1];
    unsigned short p2a = sDrow0[i2], p2b = sDrow1[i2];

    bf16x8 a0c = genA(kc0 * 32 + koff * 8, dpe0, p0a);
    bf16x8 a1c = genA(kc0 * 32 + koff * 8, dpe1, p0b);

    for (int kc = kc0; kc < kcEnd; kc += 2) {
        int i3 = idxD(kc + 3, koff);
        unsigned short p3a = sDrow0[i3], p3b = sDrow1[i3];
        bf16x8 a0n, a1n;
        if (kc + 1 < kcEnd) {
#pragma unroll
            for (int f = 0; f < 8; f++)
                bB[f] = *reinterpret_cast<const bf16x8*>(gB + ((size_t)(kc + 1) * 8 + f) * 512);
            int kb = (kc + 1) * 32 + koff * 8;
            a0n = genA(kb, dpe0, p1a);
            a1n = genA(kb, dpe1, p1b);
        }
#pragma unroll
        for (int f = 0; f < 8; f++) {
            acc0[f] = __builtin_amdgcn_mfma_f32_16x16x32_bf16(a0c, bA[f], acc0[f], 0, 0, 0);
            acc1[f] = __builtin_amdgcn_mfma_f32_16x16x32_bf16(a1c, bA[f], acc1[f], 0, 0, 0);
        }
        int i4 = idxD(kc + 4, koff);
        unsigned short p4a = sDrow0[i4], p4b = sDrow1[i4];
        if (kc + 2 < kcEnd) {
#pragma unroll
            for (int f = 0; f < 8; f++)
                bA[f] = *reinterpret_cast<const bf16x8*>(gB + ((size_t)(kc + 2) * 8 + f) * 512);
            int kb = (kc + 2) * 32 + koff * 8;
            a0c = genA(kb, dpe0, p2a);
            a1c = genA(kb, dpe1, p2b);
        }
        if (kc + 1 < kcEnd) {
#pragma unroll
            for (int f = 0; f < 8; f++) {
                acc0[f] = __builtin_amdgcn_mfma_f32_16x16x32_bf16(a0n, bB[f], acc0[f], 0, 0, 0);
                acc1[f] = __builtin_amdgcn_mfma_f32_16x16x32_bf16(a1n, bB[f], acc1[f], 0, 0, 0);
            }
        }
        p1a = p3a; p1b = p3b;
        p2a = p4a; p2b = p4b;
    }

    // write raw f32 partial
#pragma unroll
    for (int g2 = 0; g2 < 2; g2++) {
#pragma unroll
        for (int r = 0; r < 4; r++) {
            int row = geBase + g2 * 16 + koff * 4 + r;
            if (row < NE) {
                float* po = Pdst + (size_t)row * 128 + lrow;
#pragma unroll
                for (int f = 0; f < 8; f++) po[f * 16] = (g2 ? acc1[f][r] : acc0[f][r]);
            }
        }
    }
}

// ---------------- reduce partials + bias + LN (one wave per row, r20-verbatim) ----------------
__global__ __launch_bounds__(64) void k_lnred(const float* __restrict__ P0, const float* __restrict__ P1,
                                              const float* __restrict__ eb, const float* __restrict__ gg,
                                              const float* __restrict__ bb, float* __restrict__ outE) {
    int row = blockIdx.x, t = threadIdx.x;
    int c0 = t, c1 = t + 64;
    size_t base = (size_t)row * 128;
    float x0 = P0[base + c0] + P1[base + c0] + eb[c0];
    float x1 = P0[base + c1] + P1[base + c1] + eb[c1];
    float sum = x0 + x1;
#pragma unroll
    for (int m = 32; m; m >>= 1) sum += __shfl_xor(sum, m);
    float mean = sum * (1.f / 128.f);
    float d0 = x0 - mean, d1 = x1 - mean;
    float vs = d0*d0 + d1*d1;
#pragma unroll
    for (int m = 32; m; m >>= 1) vs += __shfl_xor(vs, m);
    float inv = 1.f / sqrtf(vs * (1.f / 128.f) + 1e-5f);
    outE[base + c0] = d0 * inv * gg[c0] + bb[c0];
    outE[base + c1] = d1 * inv * gg[c1] + bb[c1];
}

extern "C" void kernel_launch(void* const* d_in, const int* in_sizes, int n_in,
                              void* d_out, int out_size, void* d_ws, size_t ws_size,
                              hipStream_t stream) {
    const float* X       = (const float*)d_in[0];
    const int*   S       = (const int*)d_in[1];
    const float* BB      = (const float*)d_in[2];
    const float* mask    = (const float*)d_in[3];
    const float* node_w  = (const float*)d_in[4];
    const float* node_b  = (const float*)d_in[5];
    const float* node_g  = (const float*)d_in[6];
    const float* node_lb = (const float*)d_in[7];
    const float* edge_w  = (const float*)d_in[8];
    const float* edge_b  = (const float*)d_in[9];
    const float* edge_g  = (const float*)d_in[10];
    const float* edge_lb = (const float*)d_in[11];
    int N  = in_sizes[1];       // 1024
    int NE = N * TOPK;
    int nEB = (NE + EPB - 1) / EPB;     // 960

    float* out  = (float*)d_out;
    float* outV = out;                                  // N*128 f32
    float* outE = out + (size_t)N * 128;                // NE*128 f32 (doubles as P0)
    float* outI = outE + (size_t)NE * 128;              // NE f32

    char* ws = (char*)d_ws;
    int* Eidx = (int*)ws;
    size_t off = ((size_t)NE * 4 + 255) & ~(size_t)255;
    float* Xa = (float*)(ws + off);
    off += (((size_t)N * NAT * 3 * 4) + 255) & ~(size_t)255;
    unsigned short* Wt2 = (unsigned short*)(ws + off);  // WT2N*8 bf16 = 811008 B
    off += ((size_t)WT2N * 8 * 2 + 255) & ~(size_t)255;
    float* P1 = (float*)(ws + off);                     // NE*128 f32 = 15.73 MB partial

    int prepBlocks = (N + 255) / 256;
    int nodeBlocks = (N + 3) / 4;
    int frontBlocks = N + WT2_BLOCKS + prepBlocks + nodeBlocks;
    k_front<<<dim3(frontBlocks), dim3(256), 0, stream>>>(X, mask, Eidx, outI, Xa, edge_w, Wt2,
                                                         S, BB, node_w, node_b, node_g, node_lb, outV, N);
    k_edge<<<dim3(nEB * 2), dim3(64), 0, stream>>>(Xa, Eidx, Wt2, outE, P1, N);
    k_lnred<<<dim3(NE), dim3(64), 0, stream>>>(outE, P1, edge_b, edge_g, edge_lb, outE);
}

// Round 25
// 129.985 us; speedup vs baseline: 2.0499x; 1.0030x over previous
//
#include <hip/hip_runtime.h>
#include <hip/hip_bf16.h>

#define TOPK 30
#define NAT 14
#define EDGE_IN 3152   // 16 PE + 14*14*16 RBF
#define NCHUNK 99      // K chunks of 32 (3168 padded)
#define EPB 32         // edges per wave (M=32)
#define KSPLIT 50      // ks=0: [0,50), ks=1: [50,99)
#define WT2N (NCHUNK * 8 * 64)          // 50688 fragment slices
#define WT2_BLOCKS ((WT2N + 255) / 256) // 198

typedef __attribute__((ext_vector_type(8))) short bf16x8;
typedef __attribute__((ext_vector_type(4))) float f32x4;

__device__ __forceinline__ unsigned short f2bf(float f) {
    union { float f; unsigned u; } v; v.f = f;
    unsigned r = v.u + 0x7FFF + ((v.u >> 16) & 1);   // RNE
    return (unsigned short)(r >> 16);
}
__device__ __forceinline__ float bf2f(unsigned short h) {
    union { unsigned u; float f; } v; v.u = ((unsigned)h) << 16;
    return v.f;
}
__device__ __forceinline__ short cvtbf(float f) {    // proven scalar path (116 VGPR)
    __hip_bfloat16 h = __float2bfloat16(f);
    return *reinterpret_cast<short*>(&h);
}

// ---------------- merged front: KNN [0,N) + Wt2 pack + Xa prep + node (r24-proven) ----------------
__global__ __launch_bounds__(256) void k_front(const float* __restrict__ X, const float* __restrict__ mask,
                                               int* __restrict__ Eidx, float* __restrict__ outI,
                                               float* __restrict__ Xa,
                                               const float* __restrict__ EW, unsigned short* __restrict__ Wt2,
                                               const int* __restrict__ S, const float* __restrict__ BB,
                                               const float* __restrict__ NW, const float* __restrict__ nb,
                                               const float* __restrict__ ng, const float* __restrict__ nbe,
                                               float* __restrict__ outV, int N) {
    __shared__ double sCd[128];
    __shared__ int    sCj[128];
    int b = blockIdx.x;
    if (b < N) {
        int i = b, t = threadIdx.x;
        int w = t >> 6, ln = t & 63;
        double mi = (double)mask[i];
        double xx = (double)X[((size_t)i * NAT + 1) * 3 + 0];
        double xy = (double)X[((size_t)i * NAT + 1) * 3 + 1];
        double xz = (double)X[((size_t)i * NAT + 1) * 3 + 2];
        double dv[4];
#pragma unroll
        for (int k = 0; k < 4; k++) {
            int j = w * 256 + ln + 64 * k;
            if (j < N) {
                double dx = xx - (double)X[((size_t)j * NAT + 1) * 3 + 0];
                double dy = xy - (double)X[((size_t)j * NAT + 1) * 3 + 1];
                double dz = xz - (double)X[((size_t)j * NAT + 1) * 3 + 2];
                double sq = ((dx * dx + dy * dy) + dz * dz) + 1e-6;
                double m2 = mi * (double)mask[j];
                dv[k] = (m2 == 0.0) ? 1e300 : sq;   // order-equivalent key
            } else dv[k] = 1e300;
        }
        for (int s = 0; s < TOPK; s++) {
            double bd = dv[0]; int bj = w * 256 + ln;
            if (dv[1] < bd) { bd = dv[1]; bj = w * 256 + ln + 64; }
            if (dv[2] < bd) { bd = dv[2]; bj = w * 256 + ln + 128; }
            if (dv[3] < bd) { bd = dv[3]; bj = w * 256 + ln + 192; }
#pragma unroll
            for (int m = 32; m; m >>= 1) {
                double od = __shfl_xor(bd, m);
                int oj = __shfl_xor(bj, m);
                if (od < bd || (od == bd && oj < bj)) { bd = od; bj = oj; }
            }
            if (ln == 0) { sCd[w * TOPK + s] = bd; sCj[w * TOPK + s] = bj; }
            int rel = bj - w * 256 - ln;
            if (rel == 0)        dv[0] = 1e301;
            else if (rel == 64)  dv[1] = 1e301;
            else if (rel == 128) dv[2] = 1e301;
            else if (rel == 192) dv[3] = 1e301;
        }
        __syncthreads();
        if (w == 0) {
            double c0 = (ln < 4 * TOPK) ? sCd[ln] : 1e301;
            int    j0 = (ln < 4 * TOPK) ? sCj[ln] : 0x7FFFFFFF;
            int l1 = ln + 64;
            double c1 = (l1 < 4 * TOPK) ? sCd[l1] : 1e301;
            int    j1 = (l1 < 4 * TOPK) ? sCj[l1] : 0x7FFFFFFF;
            for (int s = 0; s < TOPK; s++) {
                double bd = c0; int bj = j0;
                if (c1 < bd || (c1 == bd && j1 < bj)) { bd = c1; bj = j1; }
#pragma unroll
                for (int m = 32; m; m >>= 1) {
                    double od = __shfl_xor(bd, m);
                    int oj = __shfl_xor(bj, m);
                    if (od < bd || (od == bd && oj < bj)) { bd = od; bj = oj; }
                }
                if (ln == 0) {
                    Eidx[(size_t)i * TOPK + s] = bj;
                    outI[(size_t)i * TOPK + s] = (float)bj;
                }
                if (j0 == bj) c0 = 1e301;
                if (j1 == bj) c1 = 1e301;
            }
        }
        return;
    }
    b -= N;
    if (b < WT2_BLOCKS) {
        int gid = b * 256 + threadIdx.x;
        if (gid >= WT2N) return;
        int ln = gid & 63;
        int kcf = gid >> 6;
        int kc = kcf >> 3, f = kcf & 7;
        int c = f * 16 + (ln & 15);
        int k0 = kc * 32 + (ln >> 4) * 8;
        bf16x8 o;
#pragma unroll
        for (int e = 0; e < 8; e++) {
            int k = k0 + e;
            float v = (k < EDGE_IN) ? EW[(size_t)k * 128 + c] : 0.f;
            o[e] = (short)f2bf(v);
        }
        *reinterpret_cast<bf16x8*>(Wt2 + (size_t)gid * 8) = o;
        return;
    }
    b -= WT2_BLOCKS;
    int prepBlocks = (N + 255) / 256;
    if (b < prepBlocks) {
        int i = b * 256 + threadIdx.x;
        if (i >= N) return;
        const float* xi = X + (size_t)i * NAT * 3;
        float* xo = Xa + (size_t)i * NAT * 3;
        float Nx = xi[0], Ny = xi[1], Nz = xi[2];
        float Ax = xi[3], Ay = xi[4], Az = xi[5];
        float Cx = xi[6], Cy = xi[7], Cz = xi[8];
        float bx = Ax - Nx, by = Ay - Ny, bz = Az - Nz;
        float cx = Cx - Ax, cy = Cy - Ay, cz = Cz - Az;
        float ax = by * cz - bz * cy;
        float ay = bz * cx - bx * cz;
        float az = bx * cy - by * cx;
        float Cbx = -0.58273431f * ax + 0.56802827f * bx - 0.54067466f * cx + Ax;
        float Cby = -0.58273431f * ay + 0.56802827f * by - 0.54067466f * cy + Ay;
        float Cbz = -0.58273431f * az + 0.56802827f * bz - 0.54067466f * cz + Az;
#pragma unroll
        for (int a = 0; a < 4; a++) { xo[a*3] = xi[a*3]; xo[a*3+1] = xi[a*3+1]; xo[a*3+2] = xi[a*3+2]; }
        xo[12] = Cbx; xo[13] = Cby; xo[14] = Cbz;
#pragma unroll
        for (int a = 5; a < 14; a++) { xo[a*3] = xi[a*3]; xo[a*3+1] = xi[a*3+1]; xo[a*3+2] = xi[a*3+2]; }
        return;
    }
    b -= prepBlocks;
    int i = b * 4 + (threadIdx.x >> 6);
    if (i >= N) return;
    int t = threadIdx.x & 63;
    int s = S[i];
    float b0 = BB[i*6], b1 = BB[i*6+1], b2 = BB[i*6+2], b3 = BB[i*6+3], b4 = BB[i*6+4], b5 = BB[i*6+5];
    int t2 = t + 64;
    float x0 = NW[(size_t)s*128 + t] + nb[t]
             + b0*NW[21*128+t] + b1*NW[22*128+t] + b2*NW[23*128+t]
             + b3*NW[24*128+t] + b4*NW[25*128+t] + b5*NW[26*128+t];
    float x1 = NW[(size_t)s*128 + t2] + nb[t2]
             + b0*NW[21*128+t2] + b1*NW[22*128+t2] + b2*NW[23*128+t2]
             + b3*NW[24*128+t2] + b4*NW[25*128+t2] + b5*NW[26*128+t2];
    float sum = x0 + x1;
#pragma unroll
    for (int m = 32; m; m >>= 1) sum += __shfl_xor(sum, m);
    float mean = sum * (1.f / 128.f);
    float d0 = x0 - mean, d1 = x1 - mean;
    float vs = d0*d0 + d1*d1;
#pragma unroll
    for (int m = 32; m; m >>= 1) vs += __shfl_xor(vs, m);
    float inv = 1.f / sqrtf(vs * (1.f / 128.f) + 1e-5f);
    outV[(size_t)i*128 + t]  = d0 * inv * ng[t]  + nbe[t];
    outV[(size_t)i*128 + t2] = d1 * inv * ng[t2] + nbe[t2];
}

// ---------------- A-fragment generator with Gaussian-ratio recurrence (r23-proven) ----------------
__device__ __forceinline__ bf16x8 genA(int kb, float dpe, unsigned short du) {
    const float FR[8] = {1.0f, 0.31622776601683794f, 0.1f, 0.03162277660168379f,
                         0.01f, 0.0031622776601683794f, 0.001f, 0.00031622776601683794f};
    const float CS = 0.96089796f;     // 0.8*sqrt(log2 e)
    const float CJ = 1.28119728f;     // (4/3)*CS
    const float C2 = 1.6414664f;      // CJ^2
    const float TC = 2.5623946f;      // 2*CJ
    const float Q1 = 0.10272918f;     // exp2(-2*CJ^2)
    const float Q4 = 1.1141460e-4f;   // exp2(-8*CJ^2)
    bf16x8 a;
    if (kb < 16) {
#pragma unroll
        for (int jj = 0; jj < 8; jj++) {
            float ang = dpe * FR[jj];
            a[jj] = cvtbf((kb == 0) ? cosf(ang) : sinf(ang));
        }
    } else if (kb >= EDGE_IN) {
#pragma unroll
        for (int jj = 0; jj < 8; jj++) a[jj] = 0;
    } else {
        float D = bf2f(du);
        float bse = (float)((kb - 16) & 15);
        float u0 = fminf(D * CS - bse * CJ, 16.f);   // clamp: beyond -> < 2e-15
        float u4 = u0 - 4.f * CJ;
        float e0 = __builtin_amdgcn_exp2f(-u0 * u0);
        float t0 = __builtin_amdgcn_exp2f(TC * u0 - C2);
        float e4 = __builtin_amdgcn_exp2f(-u4 * u4);
        float t4 = t0 * Q4;
        float e1 = e0 * t0;  float t1 = t0 * Q1;
        float e2 = e1 * t1;  float t2 = t1 * Q1;
        float e3 = e2 * t2;
        float e5 = e4 * t4;  float t5 = t4 * Q1;
        float e6 = e5 * t5;  float t6 = t5 * Q1;
        float e7 = e6 * t6;
        a[0] = cvtbf(e0); a[1] = cvtbf(e1); a[2] = cvtbf(e2); a[3] = cvtbf(e3);
        a[4] = cvtbf(e4); a[5] = cvtbf(e5); a[6] = cvtbf(e6); a[7] = cvtbf(e7);
    }
    return a;
}

__device__ __forceinline__ int idxD(int kc, int koff) {
    int idx = 2 * kc + (koff >> 1) - 1;
    return idx < 0 ? 0 : (idx > 195 ? 195 : idx);
}

// ---------------- fused edge features + bf16 MFMA GEMM (K-split-2, 2 waves/block) ----------------
// 960 blocks x 128 threads: blockIdx = (ebPair<<1)|ks; wave wid owns edge-group
// eb = ebPair*2+wid. Two fully independent waves per block (own LDS half, zero
// barriers) — packs the fixed 1920-wave supply into fewer blocks to get under
// the ~5-6 block/CU residency ceiling observed in r20/r22.
__global__ __launch_bounds__(128) void k_edge(const float* __restrict__ Xa, const int* __restrict__ Eidx,
                                              const unsigned short* __restrict__ Wt2,
                                              float* __restrict__ P0, float* __restrict__ P1, int N) {
    __shared__ unsigned short sDh[2][EPB * 200];         // per-wave D table, 2 x 12.8 KB
    __shared__ float sDpe[2][EPB];
    const int NE = N * TOPK;
    int wid = threadIdx.x >> 6, t = threadIdx.x & 63;    // wave id, lane
    int ebPair = blockIdx.x >> 1, ks = blockIdx.x & 1;
    int eb = ebPair * 2 + wid;
    int geBase = eb * EPB;
    int kc0 = ks ? KSPLIT : 0;
    int kcEnd = ks ? NCHUNK : KSPLIT;
    float* Pdst = ks ? P1 : P0;
    unsigned short* myDh = sDh[wid];
    float* myDpe = sDpe[wid];

    const unsigned short* gB = Wt2 + (size_t)t * 8;      // lane fragment base

    bf16x8 bA[8], bB[8];
#pragma unroll
    for (int f = 0; f < 8; f++)
        bA[f] = *reinterpret_cast<const bf16x8*>(gB + ((size_t)kc0 * 8 + f) * 512);

    // D-table build (wave-private): 2 lanes per edge, 98 pair-distances each
    {
        int le = t >> 1, q = t & 1;
        int ge = geBase + le; if (ge >= NE) ge = NE - 1;
        int i = ge / TOPK;
        int j = Eidx[ge];
        if (q == 0) myDpe[le] = (float)j - (float)i;
        const float* Xi = Xa + (size_t)i * NAT * 3;
        const float* Xj = Xa + (size_t)j * NAT * 3;
        for (int p = q; p < 196; p += 2) {
            int a = p / 14, b2 = p - 14 * a;
            float dx = Xi[a*3+0] - Xj[b2*3+0];
            float dy = Xi[a*3+1] - Xj[b2*3+1];
            float dz = Xi[a*3+2] - Xj[b2*3+2];
            myDh[le * 200 + p] = f2bf(sqrtf(dx*dx + dy*dy + dz*dz + 1e-6f));
        }
    }
    asm volatile("s_waitcnt lgkmcnt(0)" ::: "memory");   // this wave's ds_writes done

    int lrow = t & 15, koff = t >> 4;
    const unsigned short* sDrow0 = myDh + (size_t)lrow * 200;
    const unsigned short* sDrow1 = myDh + (size_t)(lrow + 16) * 200;
    float dpe0 = myDpe[lrow];
    float dpe1 = myDpe[lrow + 16];

    f32x4 acc0[8], acc1[8];
#pragma unroll
    for (int f = 0; f < 8; f++) { acc0[f] = (f32x4){0.f,0.f,0.f,0.f}; acc1[f] = (f32x4){0.f,0.f,0.f,0.f}; }

    int i0 = idxD(kc0, koff), i1 = idxD(kc0 + 1, koff), i2 = idxD(kc0 + 2, koff);
    unsigned short p0a = sDrow0[i0], p0b = sDrow1[i0];
    unsigned short p1a = sDrow0[i1], p1b = sDrow1[i1];
    unsigned short p2a = sDrow0[i2], p2b = sDrow1[i2];

    bf16x8 a0c = genA(kc0 * 32 + koff * 8, dpe0, p0a);
    bf16x8 a1c = genA(kc0 * 32 + koff * 8, dpe1, p0b);

    for (int kc = kc0; kc < kcEnd; kc += 2) {
        int i3 = idxD(kc + 3, koff);
        unsigned short p3a = sDrow0[i3], p3b = sDrow1[i3];
        bf16x8 a0n, a1n;
        if (kc + 1 < kcEnd) {
#pragma unroll
            for (int f = 0; f < 8; f++)
                bB[f] = *reinterpret_cast<const bf16x8*>(gB + ((size_t)(kc + 1) * 8 + f) * 512);
            int kb = (kc + 1) * 32 + koff * 8;
            a0n = genA(kb, dpe0, p1a);
            a1n = genA(kb, dpe1, p1b);
        }
#pragma unroll
        for (int f = 0; f < 8; f++) {
            acc0[f] = __builtin_amdgcn_mfma_f32_16x16x32_bf16(a0c, bA[f], acc0[f], 0, 0, 0);
            acc1[f] = __builtin_amdgcn_mfma_f32_16x16x32_bf16(a1c, bA[f], acc1[f], 0, 0, 0);
        }
        int i4 = idxD(kc + 4, koff);
        unsigned short p4a = sDrow0[i4], p4b = sDrow1[i4];
        if (kc + 2 < kcEnd) {
#pragma unroll
            for (int f = 0; f < 8; f++)
                bA[f] = *reinterpret_cast<const bf16x8*>(gB + ((size_t)(kc + 2) * 8 + f) * 512);
            int kb = (kc + 2) * 32 + koff * 8;
            a0c = genA(kb, dpe0, p2a);
            a1c = genA(kb, dpe1, p2b);
        }
        if (kc + 1 < kcEnd) {
#pragma unroll
            for (int f = 0; f < 8; f++) {
                acc0[f] = __builtin_amdgcn_mfma_f32_16x16x32_bf16(a0n, bB[f], acc0[f], 0, 0, 0);
                acc1[f] = __builtin_amdgcn_mfma_f32_16x16x32_bf16(a1n, bB[f], acc1[f], 0, 0, 0);
            }
        }
        p1a = p3a; p1b = p3b;
        p2a = p4a; p2b = p4b;
    }

    // write raw f32 partial
#pragma unroll
    for (int g2 = 0; g2 < 2; g2++) {
#pragma unroll
        for (int r = 0; r < 4; r++) {
            int row = geBase + g2 * 16 + koff * 4 + r;
            if (row < NE) {
                float* po = Pdst + (size_t)row * 128 + lrow;
#pragma unroll
                for (int f = 0; f < 8; f++) po[f * 16] = (g2 ? acc1[f][r] : acc0[f][r]);
            }
        }
    }
}

// ---------------- reduce partials + bias + LN (one wave per row, r20-verbatim) ----------------
__global__ __launch_bounds__(64) void k_lnred(const float* __restrict__ P0, const float* __restrict__ P1,
                                              const float* __restrict__ eb, const float* __restrict__ gg,
                                              const float* __restrict__ bb, float* __restrict__ outE) {
    int row = blockIdx.x, t = threadIdx.x;
    int c0 = t, c1 = t + 64;
    size_t base = (size_t)row * 128;
    float x0 = P0[base + c0] + P1[base + c0] + eb[c0];
    float x1 = P0[base + c1] + P1[base + c1] + eb[c1];
    float sum = x0 + x1;
#pragma unroll
    for (int m = 32; m; m >>= 1) sum += __shfl_xor(sum, m);
    float mean = sum * (1.f / 128.f);
    float d0 = x0 - mean, d1 = x1 - mean;
    float vs = d0*d0 + d1*d1;
#pragma unroll
    for (int m = 32; m; m >>= 1) vs += __shfl_xor(vs, m);
    float inv = 1.f / sqrtf(vs * (1.f / 128.f) + 1e-5f);
    outE[base + c0] = d0 * inv * gg[c0] + bb[c0];
    outE[base + c1] = d1 * inv * gg[c1] + bb[c1];
}

extern "C" void kernel_launch(void* const* d_in, const int* in_sizes, int n_in,
                              void* d_out, int out_size, void* d_ws, size_t ws_size,
                              hipStream_t stream) {
    const float* X       = (const float*)d_in[0];
    const int*   S       = (const int*)d_in[1];
    const float* BB      = (const float*)d_in[2];
    const float* mask    = (const float*)d_in[3];
    const float* node_w  = (const float*)d_in[4];
    const float* node_b  = (const float*)d_in[5];
    const float* node_g  = (const float*)d_in[6];
    const float* node_lb = (const float*)d_in[7];
    const float* edge_w  = (const float*)d_in[8];
    const float* edge_b  = (const float*)d_in[9];
    const float* edge_g  = (const float*)d_in[10];
    const float* edge_lb = (const float*)d_in[11];
    int N  = in_sizes[1];       // 1024
    int NE = N * TOPK;
    int nEB = (NE + EPB - 1) / EPB;     // 960 edge groups; pairs = 480

    float* out  = (float*)d_out;
    float* outV = out;                                  // N*128 f32
    float* outE = out + (size_t)N * 128;                // NE*128 f32 (doubles as P0)
    float* outI = outE + (size_t)NE * 128;              // NE f32

    char* ws = (char*)d_ws;
    int* Eidx = (int*)ws;
    size_t off = ((size_t)NE * 4 + 255) & ~(size_t)255;
    float* Xa = (float*)(ws + off);
    off += (((size_t)N * NAT * 3 * 4) + 255) & ~(size_t)255;
    unsigned short* Wt2 = (unsigned short*)(ws + off);  // WT2N*8 bf16 = 811008 B
    off += ((size_t)WT2N * 8 * 2 + 255) & ~(size_t)255;
    float* P1 = (float*)(ws + off);                     // NE*128 f32 = 15.73 MB partial

    int prepBlocks = (N + 255) / 256;
    int nodeBlocks = (N + 3) / 4;
    int frontBlocks = N + WT2_BLOCKS + prepBlocks + nodeBlocks;
    k_front<<<dim3(frontBlocks), dim3(256), 0, stream>>>(X, mask, Eidx, outI, Xa, edge_w, Wt2,
                                                         S, BB, node_w, node_b, node_g, node_lb, outV, N);
    k_edge<<<dim3(nEB), dim3(128), 0, stream>>>(Xa, Eidx, Wt2, outE, P1, N);   // 960 blocks x 2 waves
    k_lnred<<<dim3(NE), dim3(64), 0, stream>>>(outE, P1, edge_b, edge_g, edge_lb, outE);
}

// Round 26
// 127.413 us; speedup vs baseline: 2.0912x; 1.0202x over previous
//
#include <hip/hip_runtime.h>
#include <hip/hip_bf16.h>

#define TOPK 30
#define NAT 14
#define EDGE_IN 3152   // 16 PE + 14*14*16 RBF
#define NCHUNK 99      // K chunks of 32 (3168 padded)
#define EPB 32         // edges per wave (M=32)
#define KSPLIT 50      // ks=0: [0,50), ks=1: [50,99)
#define WT2N (NCHUNK * 8 * 64)          // 50688 fragment slices
#define WT2_BLOCKS ((WT2N + 255) / 256) // 198

typedef __attribute__((ext_vector_type(8))) short bf16x8;
typedef __attribute__((ext_vector_type(4))) float f32x4;

__device__ __forceinline__ unsigned short f2bf(float f) {
    union { float f; unsigned u; } v; v.f = f;
    unsigned r = v.u + 0x7FFF + ((v.u >> 16) & 1);   // RNE
    return (unsigned short)(r >> 16);
}
__device__ __forceinline__ float bf2f(unsigned short h) {
    union { unsigned u; float f; } v; v.u = ((unsigned)h) << 16;
    return v.f;
}
__device__ __forceinline__ short cvtbf(float f) {    // proven scalar path (116 VGPR)
    __hip_bfloat16 h = __float2bfloat16(f);
    return *reinterpret_cast<short*>(&h);
}

// ---------------- merged front: KNN [0,N) + Wt2 pack + Xa prep + node (r24-proven) ----------------
__global__ __launch_bounds__(256) void k_front(const float* __restrict__ X, const float* __restrict__ mask,
                                               int* __restrict__ Eidx, float* __restrict__ outI,
                                               float* __restrict__ Xa,
                                               const float* __restrict__ EW, unsigned short* __restrict__ Wt2,
                                               const int* __restrict__ S, const float* __restrict__ BB,
                                               const float* __restrict__ NW, const float* __restrict__ nb,
                                               const float* __restrict__ ng, const float* __restrict__ nbe,
                                               float* __restrict__ outV, int N) {
    __shared__ double sCd[128];
    __shared__ int    sCj[128];
    int b = blockIdx.x;
    if (b < N) {
        int i = b, t = threadIdx.x;
        int w = t >> 6, ln = t & 63;
        double mi = (double)mask[i];
        double xx = (double)X[((size_t)i * NAT + 1) * 3 + 0];
        double xy = (double)X[((size_t)i * NAT + 1) * 3 + 1];
        double xz = (double)X[((size_t)i * NAT + 1) * 3 + 2];
        double dv[4];
#pragma unroll
        for (int k = 0; k < 4; k++) {
            int j = w * 256 + ln + 64 * k;
            if (j < N) {
                double dx = xx - (double)X[((size_t)j * NAT + 1) * 3 + 0];
                double dy = xy - (double)X[((size_t)j * NAT + 1) * 3 + 1];
                double dz = xz - (double)X[((size_t)j * NAT + 1) * 3 + 2];
                double sq = ((dx * dx + dy * dy) + dz * dz) + 1e-6;
                double m2 = mi * (double)mask[j];
                dv[k] = (m2 == 0.0) ? 1e300 : sq;   // order-equivalent key
            } else dv[k] = 1e300;
        }
        for (int s = 0; s < TOPK; s++) {
            double bd = dv[0]; int bj = w * 256 + ln;
            if (dv[1] < bd) { bd = dv[1]; bj = w * 256 + ln + 64; }
            if (dv[2] < bd) { bd = dv[2]; bj = w * 256 + ln + 128; }
            if (dv[3] < bd) { bd = dv[3]; bj = w * 256 + ln + 192; }
#pragma unroll
            for (int m = 32; m; m >>= 1) {
                double od = __shfl_xor(bd, m);
                int oj = __shfl_xor(bj, m);
                if (od < bd || (od == bd && oj < bj)) { bd = od; bj = oj; }
            }
            if (ln == 0) { sCd[w * TOPK + s] = bd; sCj[w * TOPK + s] = bj; }
            int rel = bj - w * 256 - ln;
            if (rel == 0)        dv[0] = 1e301;
            else if (rel == 64)  dv[1] = 1e301;
            else if (rel == 128) dv[2] = 1e301;
            else if (rel == 192) dv[3] = 1e301;
        }
        __syncthreads();
        if (w == 0) {
            double c0 = (ln < 4 * TOPK) ? sCd[ln] : 1e301;
            int    j0 = (ln < 4 * TOPK) ? sCj[ln] : 0x7FFFFFFF;
            int l1 = ln + 64;
            double c1 = (l1 < 4 * TOPK) ? sCd[l1] : 1e301;
            int    j1 = (l1 < 4 * TOPK) ? sCj[l1] : 0x7FFFFFFF;
            for (int s = 0; s < TOPK; s++) {
                double bd = c0; int bj = j0;
                if (c1 < bd || (c1 == bd && j1 < bj)) { bd = c1; bj = j1; }
#pragma unroll
                for (int m = 32; m; m >>= 1) {
                    double od = __shfl_xor(bd, m);
                    int oj = __shfl_xor(bj, m);
                    if (od < bd || (od == bd && oj < bj)) { bd = od; bj = oj; }
                }
                if (ln == 0) {
                    Eidx[(size_t)i * TOPK + s] = bj;
                    outI[(size_t)i * TOPK + s] = (float)bj;
                }
                if (j0 == bj) c0 = 1e301;
                if (j1 == bj) c1 = 1e301;
            }
        }
        return;
    }
    b -= N;
    if (b < WT2_BLOCKS) {
        int gid = b * 256 + threadIdx.x;
        if (gid >= WT2N) return;
        int ln = gid & 63;
        int kcf = gid >> 6;
        int kc = kcf >> 3, f = kcf & 7;
        int c = f * 16 + (ln & 15);
        int k0 = kc * 32 + (ln >> 4) * 8;
        bf16x8 o;
#pragma unroll
        for (int e = 0; e < 8; e++) {
            int k = k0 + e;
            float v = (k < EDGE_IN) ? EW[(size_t)k * 128 + c] : 0.f;
            o[e] = (short)f2bf(v);
        }
        *reinterpret_cast<bf16x8*>(Wt2 + (size_t)gid * 8) = o;
        return;
    }
    b -= WT2_BLOCKS;
    int prepBlocks = (N + 255) / 256;
    if (b < prepBlocks) {
        int i = b * 256 + threadIdx.x;
        if (i >= N) return;
        const float* xi = X + (size_t)i * NAT * 3;
        float* xo = Xa + (size_t)i * NAT * 3;
        float Nx = xi[0], Ny = xi[1], Nz = xi[2];
        float Ax = xi[3], Ay = xi[4], Az = xi[5];
        float Cx = xi[6], Cy = xi[7], Cz = xi[8];
        float bx = Ax - Nx, by = Ay - Ny, bz = Az - Nz;
        float cx = Cx - Ax, cy = Cy - Ay, cz = Cz - Az;
        float ax = by * cz - bz * cy;
        float ay = bz * cx - bx * cz;
        float az = bx * cy - by * cx;
        float Cbx = -0.58273431f * ax + 0.56802827f * bx - 0.54067466f * cx + Ax;
        float Cby = -0.58273431f * ay + 0.56802827f * by - 0.54067466f * cy + Ay;
        float Cbz = -0.58273431f * az + 0.56802827f * bz - 0.54067466f * cz + Az;
#pragma unroll
        for (int a = 0; a < 4; a++) { xo[a*3] = xi[a*3]; xo[a*3+1] = xi[a*3+1]; xo[a*3+2] = xi[a*3+2]; }
        xo[12] = Cbx; xo[13] = Cby; xo[14] = Cbz;
#pragma unroll
        for (int a = 5; a < 14; a++) { xo[a*3] = xi[a*3]; xo[a*3+1] = xi[a*3+1]; xo[a*3+2] = xi[a*3+2]; }
        return;
    }
    b -= prepBlocks;
    int i = b * 4 + (threadIdx.x >> 6);
    if (i >= N) return;
    int t = threadIdx.x & 63;
    int s = S[i];
    float b0 = BB[i*6], b1 = BB[i*6+1], b2 = BB[i*6+2], b3 = BB[i*6+3], b4 = BB[i*6+4], b5 = BB[i*6+5];
    int t2 = t + 64;
    float x0 = NW[(size_t)s*128 + t] + nb[t]
             + b0*NW[21*128+t] + b1*NW[22*128+t] + b2*NW[23*128+t]
             + b3*NW[24*128+t] + b4*NW[25*128+t] + b5*NW[26*128+t];
    float x1 = NW[(size_t)s*128 + t2] + nb[t2]
             + b0*NW[21*128+t2] + b1*NW[22*128+t2] + b2*NW[23*128+t2]
             + b3*NW[24*128+t2] + b4*NW[25*128+t2] + b5*NW[26*128+t2];
    float sum = x0 + x1;
#pragma unroll
    for (int m = 32; m; m >>= 1) sum += __shfl_xor(sum, m);
    float mean = sum * (1.f / 128.f);
    float d0 = x0 - mean, d1 = x1 - mean;
    float vs = d0*d0 + d1*d1;
#pragma unroll
    for (int m = 32; m; m >>= 1) vs += __shfl_xor(vs, m);
    float inv = 1.f / sqrtf(vs * (1.f / 128.f) + 1e-5f);
    outV[(size_t)i*128 + t]  = d0 * inv * ng[t]  + nbe[t];
    outV[(size_t)i*128 + t2] = d1 * inv * ng[t2] + nbe[t2];
}

// ---------------- A-fragment generator with Gaussian-ratio recurrence (r23-proven) ----------------
__device__ __forceinline__ bf16x8 genA(int kb, float dpe, unsigned short du) {
    const float FR[8] = {1.0f, 0.31622776601683794f, 0.1f, 0.03162277660168379f,
                         0.01f, 0.0031622776601683794f, 0.001f, 0.00031622776601683794f};
    const float CS = 0.96089796f;     // 0.8*sqrt(log2 e)
    const float CJ = 1.28119728f;     // (4/3)*CS
    const float C2 = 1.6414664f;      // CJ^2
    const float TC = 2.5623946f;      // 2*CJ
    const float Q1 = 0.10272918f;     // exp2(-2*CJ^2)
    const float Q4 = 1.1141460e-4f;   // exp2(-8*CJ^2)
    bf16x8 a;
    if (kb < 16) {
#pragma unroll
        for (int jj = 0; jj < 8; jj++) {
            float ang = dpe * FR[jj];
            a[jj] = cvtbf((kb == 0) ? cosf(ang) : sinf(ang));
        }
    } else if (kb >= EDGE_IN) {
#pragma unroll
        for (int jj = 0; jj < 8; jj++) a[jj] = 0;
    } else {
        float D = bf2f(du);
        float bse = (float)((kb - 16) & 15);
        float u0 = fminf(D * CS - bse * CJ, 16.f);   // clamp: beyond -> < 2e-15
        float u4 = u0 - 4.f * CJ;
        float e0 = __builtin_amdgcn_exp2f(-u0 * u0);
        float t0 = __builtin_amdgcn_exp2f(TC * u0 - C2);
        float e4 = __builtin_amdgcn_exp2f(-u4 * u4);
        float t4 = t0 * Q4;
        float e1 = e0 * t0;  float t1 = t0 * Q1;
        float e2 = e1 * t1;  float t2 = t1 * Q1;
        float e3 = e2 * t2;
        float e5 = e4 * t4;  float t5 = t4 * Q1;
        float e6 = e5 * t5;  float t6 = t5 * Q1;
        float e7 = e6 * t6;
        a[0] = cvtbf(e0); a[1] = cvtbf(e1); a[2] = cvtbf(e2); a[3] = cvtbf(e3);
        a[4] = cvtbf(e4); a[5] = cvtbf(e5); a[6] = cvtbf(e6); a[7] = cvtbf(e7);
    }
    return a;
}

__device__ __forceinline__ int idxD(int kc, int koff) {
    int idx = 2 * kc + (koff >> 1) - 1;
    return idx < 0 ? 0 : (idx > 195 ? 195 : idx);
}

// ---------------- fused edge features + bf16 MFMA GEMM (K-split-2, 2 waves/block) ----------------
// r25 shape; partials now stored as bf16 (uniform single-type epilogue -> VGPR
// stays 116 per r20/r22/r24 precedent; accuracy precedent r15: absmax unchanged).
__global__ __launch_bounds__(128) void k_edge(const float* __restrict__ Xa, const int* __restrict__ Eidx,
                                              const unsigned short* __restrict__ Wt2,
                                              unsigned short* __restrict__ P0h, unsigned short* __restrict__ P1h,
                                              int N) {
    __shared__ unsigned short sDh[2][EPB * 200];         // per-wave D table, 2 x 12.8 KB
    __shared__ float sDpe[2][EPB];
    const int NE = N * TOPK;
    int wid = threadIdx.x >> 6, t = threadIdx.x & 63;    // wave id, lane
    int ebPair = blockIdx.x >> 1, ks = blockIdx.x & 1;
    int eb = ebPair * 2 + wid;
    int geBase = eb * EPB;
    int kc0 = ks ? KSPLIT : 0;
    int kcEnd = ks ? NCHUNK : KSPLIT;
    unsigned short* Pdst = ks ? P1h : P0h;
    unsigned short* myDh = sDh[wid];
    float* myDpe = sDpe[wid];

    const unsigned short* gB = Wt2 + (size_t)t * 8;      // lane fragment base

    bf16x8 bA[8], bB[8];
#pragma unroll
    for (int f = 0; f < 8; f++)
        bA[f] = *reinterpret_cast<const bf16x8*>(gB + ((size_t)kc0 * 8 + f) * 512);

    // D-table build (wave-private): 2 lanes per edge, 98 pair-distances each
    {
        int le = t >> 1, q = t & 1;
        int ge = geBase + le; if (ge >= NE) ge = NE - 1;
        int i = ge / TOPK;
        int j = Eidx[ge];
        if (q == 0) myDpe[le] = (float)j - (float)i;
        const float* Xi = Xa + (size_t)i * NAT * 3;
        const float* Xj = Xa + (size_t)j * NAT * 3;
        for (int p = q; p < 196; p += 2) {
            int a = p / 14, b2 = p - 14 * a;
            float dx = Xi[a*3+0] - Xj[b2*3+0];
            float dy = Xi[a*3+1] - Xj[b2*3+1];
            float dz = Xi[a*3+2] - Xj[b2*3+2];
            myDh[le * 200 + p] = f2bf(sqrtf(dx*dx + dy*dy + dz*dz + 1e-6f));
        }
    }
    asm volatile("s_waitcnt lgkmcnt(0)" ::: "memory");   // this wave's ds_writes done

    int lrow = t & 15, koff = t >> 4;
    const unsigned short* sDrow0 = myDh + (size_t)lrow * 200;
    const unsigned short* sDrow1 = myDh + (size_t)(lrow + 16) * 200;
    float dpe0 = myDpe[lrow];
    float dpe1 = myDpe[lrow + 16];

    f32x4 acc0[8], acc1[8];
#pragma unroll
    for (int f = 0; f < 8; f++) { acc0[f] = (f32x4){0.f,0.f,0.f,0.f}; acc1[f] = (f32x4){0.f,0.f,0.f,0.f}; }

    int i0 = idxD(kc0, koff), i1 = idxD(kc0 + 1, koff), i2 = idxD(kc0 + 2, koff);
    unsigned short p0a = sDrow0[i0], p0b = sDrow1[i0];
    unsigned short p1a = sDrow0[i1], p1b = sDrow1[i1];
    unsigned short p2a = sDrow0[i2], p2b = sDrow1[i2];

    bf16x8 a0c = genA(kc0 * 32 + koff * 8, dpe0, p0a);
    bf16x8 a1c = genA(kc0 * 32 + koff * 8, dpe1, p0b);

    for (int kc = kc0; kc < kcEnd; kc += 2) {
        int i3 = idxD(kc + 3, koff);
        unsigned short p3a = sDrow0[i3], p3b = sDrow1[i3];
        bf16x8 a0n, a1n;
        if (kc + 1 < kcEnd) {
#pragma unroll
            for (int f = 0; f < 8; f++)
                bB[f] = *reinterpret_cast<const bf16x8*>(gB + ((size_t)(kc + 1) * 8 + f) * 512);
            int kb = (kc + 1) * 32 + koff * 8;
            a0n = genA(kb, dpe0, p1a);
            a1n = genA(kb, dpe1, p1b);
        }
#pragma unroll
        for (int f = 0; f < 8; f++) {
            acc0[f] = __builtin_amdgcn_mfma_f32_16x16x32_bf16(a0c, bA[f], acc0[f], 0, 0, 0);
            acc1[f] = __builtin_amdgcn_mfma_f32_16x16x32_bf16(a1c, bA[f], acc1[f], 0, 0, 0);
        }
        int i4 = idxD(kc + 4, koff);
        unsigned short p4a = sDrow0[i4], p4b = sDrow1[i4];
        if (kc + 2 < kcEnd) {
#pragma unroll
            for (int f = 0; f < 8; f++)
                bA[f] = *reinterpret_cast<const bf16x8*>(gB + ((size_t)(kc + 2) * 8 + f) * 512);
            int kb = (kc + 2) * 32 + koff * 8;
            a0c = genA(kb, dpe0, p2a);
            a1c = genA(kb, dpe1, p2b);
        }
        if (kc + 1 < kcEnd) {
#pragma unroll
            for (int f = 0; f < 8; f++) {
                acc0[f] = __builtin_amdgcn_mfma_f32_16x16x32_bf16(a0n, bB[f], acc0[f], 0, 0, 0);
                acc1[f] = __builtin_amdgcn_mfma_f32_16x16x32_bf16(a1n, bB[f], acc1[f], 0, 0, 0);
            }
        }
        p1a = p3a; p1b = p3b;
        p2a = p4a; p2b = p4b;
    }

    // write raw bf16 partial (uniform single-type store body)
#pragma unroll
    for (int g2 = 0; g2 < 2; g2++) {
#pragma unroll
        for (int r = 0; r < 4; r++) {
            int row = geBase + g2 * 16 + koff * 4 + r;
            if (row < NE) {
                unsigned short* po = Pdst + (size_t)row * 128 + lrow;
#pragma unroll
                for (int f = 0; f < 8; f++) po[f * 16] = f2bf(g2 ? acc1[f][r] : acc0[f][r]);
            }
        }
    }
}

// ---------------- reduce bf16 partials + bias + LN (one wave per row) ----------------
__global__ __launch_bounds__(64) void k_lnred(const unsigned short* __restrict__ P0h,
                                              const unsigned short* __restrict__ P1h,
                                              const float* __restrict__ eb, const float* __restrict__ gg,
                                              const float* __restrict__ bb, float* __restrict__ outE) {
    int row = blockIdx.x, t = threadIdx.x;
    int c0 = t, c1 = t + 64;
    size_t base = (size_t)row * 128;
    float x0 = bf2f(P0h[base + c0]) + bf2f(P1h[base + c0]) + eb[c0];
    float x1 = bf2f(P0h[base + c1]) + bf2f(P1h[base + c1]) + eb[c1];
    float sum = x0 + x1;
#pragma unroll
    for (int m = 32; m; m >>= 1) sum += __shfl_xor(sum, m);
    float mean = sum * (1.f / 128.f);
    float d0 = x0 - mean, d1 = x1 - mean;
    float vs = d0*d0 + d1*d1;
#pragma unroll
    for (int m = 32; m; m >>= 1) vs += __shfl_xor(vs, m);
    float inv = 1.f / sqrtf(vs * (1.f / 128.f) + 1e-5f);
    outE[base + c0] = d0 * inv * gg[c0] + bb[c0];
    outE[base + c1] = d1 * inv * gg[c1] + bb[c1];
}

extern "C" void kernel_launch(void* const* d_in, const int* in_sizes, int n_in,
                              void* d_out, int out_size, void* d_ws, size_t ws_size,
                              hipStream_t stream) {
    const float* X       = (const float*)d_in[0];
    const int*   S       = (const int*)d_in[1];
    const float* BB      = (const float*)d_in[2];
    const float* mask    = (const float*)d_in[3];
    const float* node_w  = (const float*)d_in[4];
    const float* node_b  = (const float*)d_in[5];
    const float* node_g  = (const float*)d_in[6];
    const float* node_lb = (const float*)d_in[7];
    const float* edge_w  = (const float*)d_in[8];
    const float* edge_b  = (const float*)d_in[9];
    const float* edge_g  = (const float*)d_in[10];
    const float* edge_lb = (const float*)d_in[11];
    int N  = in_sizes[1];       // 1024
    int NE = N * TOPK;
    int nEB = (NE + EPB - 1) / EPB;     // 960 edge groups; pairs = 480

    float* out  = (float*)d_out;
    float* outV = out;                                  // N*128 f32
    float* outE = out + (size_t)N * 128;                // NE*128 f32
    float* outI = outE + (size_t)NE * 128;              // NE f32

    char* ws = (char*)d_ws;
    int* Eidx = (int*)ws;
    size_t off = ((size_t)NE * 4 + 255) & ~(size_t)255;
    float* Xa = (float*)(ws + off);
    off += (((size_t)N * NAT * 3 * 4) + 255) & ~(size_t)255;
    unsigned short* Wt2 = (unsigned short*)(ws + off);  // WT2N*8 bf16 = 811008 B
    off += ((size_t)WT2N * 8 * 2 + 255) & ~(size_t)255;
    unsigned short* P0h = (unsigned short*)(ws + off);  // NE*128 bf16 = 7.86 MB
    off += (((size_t)NE * 128 * 2) + 255) & ~(size_t)255;
    unsigned short* P1h = (unsigned short*)(ws + off);  // NE*128 bf16 = 7.86 MB

    int prepBlocks = (N + 255) / 256;
    int nodeBlocks = (N + 3) / 4;
    int frontBlocks = N + WT2_BLOCKS + prepBlocks + nodeBlocks;
    k_front<<<dim3(frontBlocks), dim3(256), 0, stream>>>(X, mask, Eidx, outI, Xa, edge_w, Wt2,
                                                         S, BB, node_w, node_b, node_g, node_lb, outV, N);
    k_edge<<<dim3(nEB), dim3(128), 0, stream>>>(Xa, Eidx, Wt2, P0h, P1h, N);   // 960 blocks x 2 waves
    k_lnred<<<dim3(NE), dim3(64), 0, stream>>>(P0h, P1h, edge_b, edge_g, edge_lb, outE);
}

// Round 27
// 109.755 us; speedup vs baseline: 2.4277x; 1.1609x over previous
//
#include <hip/hip_runtime.h>
#include <hip/hip_bf16.h>

#define TOPK 30
#define NAT 14
#define EDGE_IN 3152   // 16 PE + 14*14*16 RBF
#define NCHUNK 99      // K chunks of 32 (3168 padded)
#define EPB 32         // edges per wave (M=32)
#define KSPLIT 50      // ks=0: [0,50), ks=1: [50,99)
#define WT2N (NCHUNK * 8 * 64)          // 50688 fragment slices
#define WT2_BLOCKS ((WT2N + 255) / 256) // 198

typedef __attribute__((ext_vector_type(8))) short bf16x8;
typedef __attribute__((ext_vector_type(4))) float f32x4;

__device__ __forceinline__ unsigned short f2bf(float f) {
    union { float f; unsigned u; } v; v.f = f;
    unsigned r = v.u + 0x7FFF + ((v.u >> 16) & 1);   // RNE
    return (unsigned short)(r >> 16);
}
__device__ __forceinline__ float bf2f(unsigned short h) {
    union { unsigned u; float f; } v; v.u = ((unsigned)h) << 16;
    return v.f;
}
__device__ __forceinline__ short cvtbf(float f) {    // proven scalar path (116 VGPR)
    __hip_bfloat16 h = __float2bfloat16(f);
    return *reinterpret_cast<short*>(&h);
}

// ---------------- merged front: KNN [0,N) + Wt2 pack + Xa prep + node ----------------
// KNN phase 1 (r24-proven): 4 waves each produce their sorted top-30 via
// repeated min. Phase 2 (NEW): rank-based parallel merge — candidate t's
// global rank = in-list pos + sum of binary-search counts in the other 3
// sorted lists; unique (d,j) keys => exact permutation, ranks 0..29 land
// the global top-30 (any non-candidate below x would imply >=30 candidates
// below x). Serial depth ~600 cyc vs 30 butterfly rounds.
__global__ __launch_bounds__(256) void k_front(const float* __restrict__ X, const float* __restrict__ mask,
                                               int* __restrict__ Eidx, float* __restrict__ outI,
                                               float* __restrict__ Xa,
                                               const float* __restrict__ EW, unsigned short* __restrict__ Wt2,
                                               const int* __restrict__ S, const float* __restrict__ BB,
                                               const float* __restrict__ NW, const float* __restrict__ nb,
                                               const float* __restrict__ ng, const float* __restrict__ nbe,
                                               float* __restrict__ outV, int N) {
    __shared__ double sCd[128];
    __shared__ int    sCj[128];
    int b = blockIdx.x;
    if (b < N) {
        int i = b, t = threadIdx.x;
        int w = t >> 6, ln = t & 63;
        double mi = (double)mask[i];
        double xx = (double)X[((size_t)i * NAT + 1) * 3 + 0];
        double xy = (double)X[((size_t)i * NAT + 1) * 3 + 1];
        double xz = (double)X[((size_t)i * NAT + 1) * 3 + 2];
        double dv[4];
#pragma unroll
        for (int k = 0; k < 4; k++) {
            int j = w * 256 + ln + 64 * k;
            if (j < N) {
                double dx = xx - (double)X[((size_t)j * NAT + 1) * 3 + 0];
                double dy = xy - (double)X[((size_t)j * NAT + 1) * 3 + 1];
                double dz = xz - (double)X[((size_t)j * NAT + 1) * 3 + 2];
                double sq = ((dx * dx + dy * dy) + dz * dz) + 1e-6;
                double m2 = mi * (double)mask[j];
                dv[k] = (m2 == 0.0) ? 1e300 : sq;   // order-equivalent key
            } else dv[k] = 1e300;
        }
        // phase 1: per-wave top-30 (emitted in sorted order)
        for (int s = 0; s < TOPK; s++) {
            double bd = dv[0]; int bj = w * 256 + ln;
            if (dv[1] < bd) { bd = dv[1]; bj = w * 256 + ln + 64; }
            if (dv[2] < bd) { bd = dv[2]; bj = w * 256 + ln + 128; }
            if (dv[3] < bd) { bd = dv[3]; bj = w * 256 + ln + 192; }
#pragma unroll
            for (int m = 32; m; m >>= 1) {
                double od = __shfl_xor(bd, m);
                int oj = __shfl_xor(bj, m);
                if (od < bd || (od == bd && oj < bj)) { bd = od; bj = oj; }
            }
            if (ln == 0) { sCd[w * TOPK + s] = bd; sCj[w * TOPK + s] = bj; }
            int rel = bj - w * 256 - ln;
            if (rel == 0)        dv[0] = 1e301;
            else if (rel == 64)  dv[1] = 1e301;
            else if (rel == 128) dv[2] = 1e301;
            else if (rel == 192) dv[3] = 1e301;
        }
        __syncthreads();
        // phase 2: rank-select across the 4 sorted lists (lanes t < 120)
        if (t < 4 * TOPK) {
            double dx_ = sCd[t]; int jx = sCj[t];
            int li = t / TOPK;
            int rank = t - li * TOPK;          // position within own list
#pragma unroll
            for (int l = 0; l < 4; l++) {
                if (l == li) continue;
                int lo = 0, hi = TOPK;         // count entries < (dx_, jx)
                while (lo < hi) {              // uniform 5 iterations
                    int mid = (lo + hi) >> 1;
                    double dm = sCd[l * TOPK + mid];
                    int jm = sCj[l * TOPK + mid];
                    bool less = (dm < dx_) || (dm == dx_ && jm < jx);
                    if (less) lo = mid + 1; else hi = mid;
                }
                rank += lo;
            }
            if (rank < TOPK) {
                Eidx[(size_t)i * TOPK + rank] = jx;
                outI[(size_t)i * TOPK + rank] = (float)jx;
            }
        }
        return;
    }
    b -= N;
    if (b < WT2_BLOCKS) {
        int gid = b * 256 + threadIdx.x;
        if (gid >= WT2N) return;
        int ln = gid & 63;
        int kcf = gid >> 6;
        int kc = kcf >> 3, f = kcf & 7;
        int c = f * 16 + (ln & 15);
        int k0 = kc * 32 + (ln >> 4) * 8;
        bf16x8 o;
#pragma unroll
        for (int e = 0; e < 8; e++) {
            int k = k0 + e;
            float v = (k < EDGE_IN) ? EW[(size_t)k * 128 + c] : 0.f;
            o[e] = (short)f2bf(v);
        }
        *reinterpret_cast<bf16x8*>(Wt2 + (size_t)gid * 8) = o;
        return;
    }
    b -= WT2_BLOCKS;
    int prepBlocks = (N + 255) / 256;
    if (b < prepBlocks) {
        int i = b * 256 + threadIdx.x;
        if (i >= N) return;
        const float* xi = X + (size_t)i * NAT * 3;
        float* xo = Xa + (size_t)i * NAT * 3;
        float Nx = xi[0], Ny = xi[1], Nz = xi[2];
        float Ax = xi[3], Ay = xi[4], Az = xi[5];
        float Cx = xi[6], Cy = xi[7], Cz = xi[8];
        float bx = Ax - Nx, by = Ay - Ny, bz = Az - Nz;
        float cx = Cx - Ax, cy = Cy - Ay, cz = Cz - Az;
        float ax = by * cz - bz * cy;
        float ay = bz * cx - bx * cz;
        float az = bx * cy - by * cx;
        float Cbx = -0.58273431f * ax + 0.56802827f * bx - 0.54067466f * cx + Ax;
        float Cby = -0.58273431f * ay + 0.56802827f * by - 0.54067466f * cy + Ay;
        float Cbz = -0.58273431f * az + 0.56802827f * bz - 0.54067466f * cz + Az;
#pragma unroll
        for (int a = 0; a < 4; a++) { xo[a*3] = xi[a*3]; xo[a*3+1] = xi[a*3+1]; xo[a*3+2] = xi[a*3+2]; }
        xo[12] = Cbx; xo[13] = Cby; xo[14] = Cbz;
#pragma unroll
        for (int a = 5; a < 14; a++) { xo[a*3] = xi[a*3]; xo[a*3+1] = xi[a*3+1]; xo[a*3+2] = xi[a*3+2]; }
        return;
    }
    b -= prepBlocks;
    int i = b * 4 + (threadIdx.x >> 6);
    if (i >= N) return;
    int t = threadIdx.x & 63;
    int s = S[i];
    float b0 = BB[i*6], b1 = BB[i*6+1], b2 = BB[i*6+2], b3 = BB[i*6+3], b4 = BB[i*6+4], b5 = BB[i*6+5];
    int t2 = t + 64;
    float x0 = NW[(size_t)s*128 + t] + nb[t]
             + b0*NW[21*128+t] + b1*NW[22*128+t] + b2*NW[23*128+t]
             + b3*NW[24*128+t] + b4*NW[25*128+t] + b5*NW[26*128+t];
    float x1 = NW[(size_t)s*128 + t2] + nb[t2]
             + b0*NW[21*128+t2] + b1*NW[22*128+t2] + b2*NW[23*128+t2]
             + b3*NW[24*128+t2] + b4*NW[25*128+t2] + b5*NW[26*128+t2];
    float sum = x0 + x1;
#pragma unroll
    for (int m = 32; m; m >>= 1) sum += __shfl_xor(sum, m);
    float mean = sum * (1.f / 128.f);
    float d0 = x0 - mean, d1 = x1 - mean;
    float vs = d0*d0 + d1*d1;
#pragma unroll
    for (int m = 32; m; m >>= 1) vs += __shfl_xor(vs, m);
    float inv = 1.f / sqrtf(vs * (1.f / 128.f) + 1e-5f);
    outV[(size_t)i*128 + t]  = d0 * inv * ng[t]  + nbe[t];
    outV[(size_t)i*128 + t2] = d1 * inv * ng[t2] + nbe[t2];
}

// ---------------- A-fragment generator with Gaussian-ratio recurrence (r23-proven) ----------------
__device__ __forceinline__ bf16x8 genA(int kb, float dpe, unsigned short du) {
    const float FR[8] = {1.0f, 0.31622776601683794f, 0.1f, 0.03162277660168379f,
                         0.01f, 0.0031622776601683794f, 0.001f, 0.00031622776601683794f};
    const float CS = 0.96089796f;     // 0.8*sqrt(log2 e)
    const float CJ = 1.28119728f;     // (4/3)*CS
    const float C2 = 1.6414664f;      // CJ^2
    const float TC = 2.5623946f;      // 2*CJ
    const float Q1 = 0.10272918f;     // exp2(-2*CJ^2)
    const float Q4 = 1.1141460e-4f;   // exp2(-8*CJ^2)
    bf16x8 a;
    if (kb < 16) {
#pragma unroll
        for (int jj = 0; jj < 8; jj++) {
            float ang = dpe * FR[jj];
            a[jj] = cvtbf((kb == 0) ? cosf(ang) : sinf(ang));
        }
    } else if (kb >= EDGE_IN) {
#pragma unroll
        for (int jj = 0; jj < 8; jj++) a[jj] = 0;
    } else {
        float D = bf2f(du);
        float bse = (float)((kb - 16) & 15);
        float u0 = fminf(D * CS - bse * CJ, 16.f);   // clamp: beyond -> < 2e-15
        float u4 = u0 - 4.f * CJ;
        float e0 = __builtin_amdgcn_exp2f(-u0 * u0);
        float t0 = __builtin_amdgcn_exp2f(TC * u0 - C2);
        float e4 = __builtin_amdgcn_exp2f(-u4 * u4);
        float t4 = t0 * Q4;
        float e1 = e0 * t0;  float t1 = t0 * Q1;
        float e2 = e1 * t1;  float t2 = t1 * Q1;
        float e3 = e2 * t2;
        float e5 = e4 * t4;  float t5 = t4 * Q1;
        float e6 = e5 * t5;  float t6 = t5 * Q1;
        float e7 = e6 * t6;
        a[0] = cvtbf(e0); a[1] = cvtbf(e1); a[2] = cvtbf(e2); a[3] = cvtbf(e3);
        a[4] = cvtbf(e4); a[5] = cvtbf(e5); a[6] = cvtbf(e6); a[7] = cvtbf(e7);
    }
    return a;
}

__device__ __forceinline__ int idxD(int kc, int koff) {
    int idx = 2 * kc + (koff >> 1) - 1;
    return idx < 0 ? 0 : (idx > 195 ? 195 : idx);
}

// ---------------- fused edge features + bf16 MFMA GEMM (K-split-2, 2 waves/block, r26-verbatim) ----------------
__global__ __launch_bounds__(128) void k_edge(const float* __restrict__ Xa, const int* __restrict__ Eidx,
                                              const unsigned short* __restrict__ Wt2,
                                              unsigned short* __restrict__ P0h, unsigned short* __restrict__ P1h,
                                              int N) {
    __shared__ unsigned short sDh[2][EPB * 200];         // per-wave D table, 2 x 12.8 KB
    __shared__ float sDpe[2][EPB];
    const int NE = N * TOPK;
    int wid = threadIdx.x >> 6, t = threadIdx.x & 63;    // wave id, lane
    int ebPair = blockIdx.x >> 1, ks = blockIdx.x & 1;
    int eb = ebPair * 2 + wid;
    int geBase = eb * EPB;
    int kc0 = ks ? KSPLIT : 0;
    int kcEnd = ks ? NCHUNK : KSPLIT;
    unsigned short* Pdst = ks ? P1h : P0h;
    unsigned short* myDh = sDh[wid];
    float* myDpe = sDpe[wid];

    const unsigned short* gB = Wt2 + (size_t)t * 8;      // lane fragment base

    bf16x8 bA[8], bB[8];
#pragma unroll
    for (int f = 0; f < 8; f++)
        bA[f] = *reinterpret_cast<const bf16x8*>(gB + ((size_t)kc0 * 8 + f) * 512);

    // D-table build (wave-private): 2 lanes per edge, 98 pair-distances each
    {
        int le = t >> 1, q = t & 1;
        int ge = geBase + le; if (ge >= NE) ge = NE - 1;
        int i = ge / TOPK;
        int j = Eidx[ge];
        if (q == 0) myDpe[le] = (float)j - (float)i;
        const float* Xi = Xa + (size_t)i * NAT * 3;
        const float* Xj = Xa + (size_t)j * NAT * 3;
        for (int p = q; p < 196; p += 2) {
            int a = p / 14, b2 = p - 14 * a;
            float dx = Xi[a*3+0] - Xj[b2*3+0];
            float dy = Xi[a*3+1] - Xj[b2*3+1];
            float dz = Xi[a*3+2] - Xj[b2*3+2];
            myDh[le * 200 + p] = f2bf(sqrtf(dx*dx + dy*dy + dz*dz + 1e-6f));
        }
    }
    asm volatile("s_waitcnt lgkmcnt(0)" ::: "memory");   // this wave's ds_writes done

    int lrow = t & 15, koff = t >> 4;
    const unsigned short* sDrow0 = myDh + (size_t)lrow * 200;
    const unsigned short* sDrow1 = myDh + (size_t)(lrow + 16) * 200;
    float dpe0 = myDpe[lrow];
    float dpe1 = myDpe[lrow + 16];

    f32x4 acc0[8], acc1[8];
#pragma unroll
    for (int f = 0; f < 8; f++) { acc0[f] = (f32x4){0.f,0.f,0.f,0.f}; acc1[f] = (f32x4){0.f,0.f,0.f,0.f}; }

    int i0 = idxD(kc0, koff), i1 = idxD(kc0 + 1, koff), i2 = idxD(kc0 + 2, koff);
    unsigned short p0a = sDrow0[i0], p0b = sDrow1[i0];
    unsigned short p1a = sDrow0[i1], p1b = sDrow1[i1];
    unsigned short p2a = sDrow0[i2], p2b = sDrow1[i2];

    bf16x8 a0c = genA(kc0 * 32 + koff * 8, dpe0, p0a);
    bf16x8 a1c = genA(kc0 * 32 + koff * 8, dpe1, p0b);

    for (int kc = kc0; kc < kcEnd; kc += 2) {
        int i3 = idxD(kc + 3, koff);
        unsigned short p3a = sDrow0[i3], p3b = sDrow1[i3];
        bf16x8 a0n, a1n;
        if (kc + 1 < kcEnd) {
#pragma unroll
            for (int f = 0; f < 8; f++)
                bB[f] = *reinterpret_cast<const bf16x8*>(gB + ((size_t)(kc + 1) * 8 + f) * 512);
            int kb = (kc + 1) * 32 + koff * 8;
            a0n = genA(kb, dpe0, p1a);
            a1n = genA(kb, dpe1, p1b);
        }
#pragma unroll
        for (int f = 0; f < 8; f++) {
            acc0[f] = __builtin_amdgcn_mfma_f32_16x16x32_bf16(a0c, bA[f], acc0[f], 0, 0, 0);
            acc1[f] = __builtin_amdgcn_mfma_f32_16x16x32_bf16(a1c, bA[f], acc1[f], 0, 0, 0);
        }
        int i4 = idxD(kc + 4, koff);
        unsigned short p4a = sDrow0[i4], p4b = sDrow1[i4];
        if (kc + 2 < kcEnd) {
#pragma unroll
            for (int f = 0; f < 8; f++)
                bA[f] = *reinterpret_cast<const bf16x8*>(gB + ((size_t)(kc + 2) * 8 + f) * 512);
            int kb = (kc + 2) * 32 + koff * 8;
            a0c = genA(kb, dpe0, p2a);
            a1c = genA(kb, dpe1, p2b);
        }
        if (kc + 1 < kcEnd) {
#pragma unroll
            for (int f = 0; f < 8; f++) {
                acc0[f] = __builtin_amdgcn_mfma_f32_16x16x32_bf16(a0n, bB[f], acc0[f], 0, 0, 0);
                acc1[f] = __builtin_amdgcn_mfma_f32_16x16x32_bf16(a1n, bB[f], acc1[f], 0, 0, 0);
            }
        }
        p1a = p3a; p1b = p3b;
        p2a = p4a; p2b = p4b;
    }

    // write raw bf16 partial (uniform single-type store body)
#pragma unroll
    for (int g2 = 0; g2 < 2; g2++) {
#pragma unroll
        for (int r = 0; r < 4; r++) {
            int row = geBase + g2 * 16 + koff * 4 + r;
            if (row < NE) {
                unsigned short* po = Pdst + (size_t)row * 128 + lrow;
#pragma unroll
                for (int f = 0; f < 8; f++) po[f * 16] = f2bf(g2 ? acc1[f][r] : acc0[f][r]);
            }
        }
    }
}

// ---------------- reduce bf16 partials + bias + LN (4 rows per 256-thread block) ----------------
__global__ __launch_bounds__(256) void k_lnred(const unsigned short* __restrict__ P0h,
                                               const unsigned short* __restrict__ P1h,
                                               const float* __restrict__ eb, const float* __restrict__ gg,
                                               const float* __restrict__ bb, float* __restrict__ outE,
                                               int NE) {
    int wid = threadIdx.x >> 6, t = threadIdx.x & 63;
    int row = blockIdx.x * 4 + wid;
    if (row >= NE) return;
    int c0 = t, c1 = t + 64;
    size_t base = (size_t)row * 128;
    float x0 = bf2f(P0h[base + c0]) + bf2f(P1h[base + c0]) + eb[c0];
    float x1 = bf2f(P0h[base + c1]) + bf2f(P1h[base + c1]) + eb[c1];
    float sum = x0 + x1;
#pragma unroll
    for (int m = 32; m; m >>= 1) sum += __shfl_xor(sum, m);
    float mean = sum * (1.f / 128.f);
    float d0 = x0 - mean, d1 = x1 - mean;
    float vs = d0*d0 + d1*d1;
#pragma unroll
    for (int m = 32; m; m >>= 1) vs += __shfl_xor(vs, m);
    float inv = 1.f / sqrtf(vs * (1.f / 128.f) + 1e-5f);
    outE[base + c0] = d0 * inv * gg[c0] + bb[c0];
    outE[base + c1] = d1 * inv * gg[c1] + bb[c1];
}

extern "C" void kernel_launch(void* const* d_in, const int* in_sizes, int n_in,
                              void* d_out, int out_size, void* d_ws, size_t ws_size,
                              hipStream_t stream) {
    const float* X       = (const float*)d_in[0];
    const int*   S       = (const int*)d_in[1];
    const float* BB      = (const float*)d_in[2];
    const float* mask    = (const float*)d_in[3];
    const float* node_w  = (const float*)d_in[4];
    const float* node_b  = (const float*)d_in[5];
    const float* node_g  = (const float*)d_in[6];
    const float* node_lb = (const float*)d_in[7];
    const float* edge_w  = (const float*)d_in[8];
    const float* edge_b  = (const float*)d_in[9];
    const float* edge_g  = (const float*)d_in[10];
    const float* edge_lb = (const float*)d_in[11];
    int N  = in_sizes[1];       // 1024
    int NE = N * TOPK;
    int nEB = (NE + EPB - 1) / EPB;     // 960 edge groups; pairs = 480

    float* out  = (float*)d_out;
    float* outV = out;                                  // N*128 f32
    float* outE = out + (size_t)N * 128;                // NE*128 f32
    float* outI = outE + (size_t)NE * 128;              // NE f32

    char* ws = (char*)d_ws;
    int* Eidx = (int*)ws;
    size_t off = ((size_t)NE * 4 + 255) & ~(size_t)255;
    float* Xa = (float*)(ws + off);
    off += (((size_t)N * NAT * 3 * 4) + 255) & ~(size_t)255;
    unsigned short* Wt2 = (unsigned short*)(ws + off);  // WT2N*8 bf16 = 811008 B
    off += ((size_t)WT2N * 8 * 2 + 255) & ~(size_t)255;
    unsigned short* P0h = (unsigned short*)(ws + off);  // NE*128 bf16 = 7.86 MB
    off += (((size_t)NE * 128 * 2) + 255) & ~(size_t)255;
    unsigned short* P1h = (unsigned short*)(ws + off);  // NE*128 bf16 = 7.86 MB

    int prepBlocks = (N + 255) / 256;
    int nodeBlocks = (N + 3) / 4;
    int frontBlocks = N + WT2_BLOCKS + prepBlocks + nodeBlocks;
    k_front<<<dim3(frontBlocks), dim3(256), 0, stream>>>(X, mask, Eidx, outI, Xa, edge_w, Wt2,
                                                         S, BB, node_w, node_b, node_g, node_lb, outV, N);
    k_edge<<<dim3(nEB), dim3(128), 0, stream>>>(Xa, Eidx, Wt2, P0h, P1h, N);   // 960 blocks x 2 waves
    k_lnred<<<dim3((NE + 3) / 4), dim3(256), 0, stream>>>(P0h, P1h, edge_b, edge_g, edge_lb, outE, NE);
}